// Round 1
// baseline (690.496 us; speedup 1.0000x reference)
//
#include <hip/hip_runtime.h>
#include <math.h>

// Problem constants (GATModel: N=50000, E=800000, F_IN=128, HID=OUT=64, H=4)
constexpr int NNODE = 50000;
constexpr int FIN   = 128;
constexpr int HID   = 64;
constexpr int NH    = 4;
constexpr int NC    = 256;   // NH * HID
constexpr float NEG = 0.2f;

// ---------------- utility ----------------
__global__ __launch_bounds__(256) void zero_i32(int* __restrict__ p, int n) {
  int i = blockIdx.x * 256 + threadIdx.x;
  if (i < n) p[i] = 0;
}

// ---------------- CSR build (by destination) ----------------
__global__ __launch_bounds__(256) void count_deg(const int* __restrict__ ei, int* __restrict__ deg, int E) {
  int i = blockIdx.x * 256 + threadIdx.x;
  if (i < E) atomicAdd(&deg[ei[E + i]], 1);
}

__global__ __launch_bounds__(1024) void scan_deg(const int* __restrict__ deg, int* __restrict__ offs,
                                                 int* __restrict__ cursor, int n) {
  __shared__ int sd[1024];
  int tid = threadIdx.x;
  const int CH = (NNODE + 1023) / 1024;  // 49
  int base = tid * CH;
  int s = 0;
  for (int i = 0; i < CH; ++i) { int idx = base + i; if (idx < n) s += deg[idx]; }
  sd[tid] = s;
  __syncthreads();
  for (int o = 1; o < 1024; o <<= 1) {
    int v = (tid >= o) ? sd[tid - o] : 0;
    __syncthreads();
    sd[tid] += v;
    __syncthreads();
  }
  int run = sd[tid] - s;  // exclusive prefix
  for (int i = 0; i < CH; ++i) {
    int idx = base + i;
    if (idx < n) { offs[idx] = run; cursor[idx] = run; run += deg[idx]; }
  }
  if (tid == 1023) offs[n] = sd[1023];
}

__global__ __launch_bounds__(256) void scatter_edges(const int* __restrict__ ei, int* __restrict__ cursor,
                                                     int* __restrict__ csr_src, int E) {
  int i = blockIdx.x * 256 + threadIdx.x;
  if (i < E) {
    int dst = ei[E + i];
    int pos = atomicAdd(&cursor[dst], 1);
    csr_src[pos] = ei[i];
  }
}

// ---------------- fp32 tiled GEMM: C[M,256] = A[M,K] @ B[K,256] ----------------
#define BM 64
#define BN 64
#define BKK 32
__global__ __launch_bounds__(256) void gemm_kernel(const float* __restrict__ A, const float* __restrict__ B,
                                                   float* __restrict__ C, int M, int K) {
  __shared__ float As[BKK][BM + 1];  // [k][row], padded
  __shared__ float Bs[BKK][BN];
  int tid = threadIdx.x;
  int row0 = blockIdx.y * BM;
  int col0 = blockIdx.x * BN;
  int tx = tid & 15, ty = tid >> 4;
  float acc[4][4] = {};
  for (int k0 = 0; k0 < K; k0 += BKK) {
#pragma unroll
    for (int p = 0; p < 2; ++p) {  // A tile: 64 rows x 32 k
      int r = p * 32 + (tid >> 3);
      int kk = (tid & 7) * 4;
      float4 v = make_float4(0.f, 0.f, 0.f, 0.f);
      int gr = row0 + r;
      if (gr < M) v = *(const float4*)(A + (size_t)gr * K + k0 + kk);
      As[kk + 0][r] = v.x; As[kk + 1][r] = v.y; As[kk + 2][r] = v.z; As[kk + 3][r] = v.w;
    }
#pragma unroll
    for (int p = 0; p < 2; ++p) {  // B tile: 32 k x 64 cols
      int kk = p * 16 + (tid >> 4);
      int c = (tid & 15) * 4;
      float4 v = *(const float4*)(B + (size_t)(k0 + kk) * NC + col0 + c);
      *(float4*)(&Bs[kk][c]) = v;
    }
    __syncthreads();
#pragma unroll
    for (int k = 0; k < BKK; ++k) {
      float a[4], b[4];
#pragma unroll
      for (int i = 0; i < 4; ++i) a[i] = As[k][ty * 4 + i];
#pragma unroll
      for (int j = 0; j < 4; ++j) b[j] = Bs[k][tx * 4 + j];
#pragma unroll
      for (int i = 0; i < 4; ++i)
#pragma unroll
        for (int j = 0; j < 4; ++j) acc[i][j] += a[i] * b[j];
    }
    __syncthreads();
  }
#pragma unroll
  for (int i = 0; i < 4; ++i) {
    int gr = row0 + ty * 4 + i;
    if (gr >= M) continue;
    *(float4*)(C + (size_t)gr * NC + col0 + tx * 4) =
        make_float4(acc[i][0], acc[i][1], acc[i][2], acc[i][3]);
  }
}

// ---------------- per-node attention halves ----------------
__device__ inline float wave_sum(float v) {
#pragma unroll
  for (int o = 32; o >= 1; o >>= 1) v += __shfl_xor(v, o);
  return v;
}

__global__ __launch_bounds__(256) void alpha_kernel(const float* __restrict__ hfeat,
                                                    const float* __restrict__ a_s, const float* __restrict__ a_d,
                                                    float* __restrict__ al_s, float* __restrict__ al_d, int n) {
  int lane = threadIdx.x & 63;
  int node = blockIdx.x * 4 + (threadIdx.x >> 6);
  if (node >= n) return;
  const float* hp = hfeat + (size_t)node * NC;
#pragma unroll
  for (int h = 0; h < NH; ++h) {
    float v = hp[h * HID + lane];
    float ps = wave_sum(v * a_s[h * HID + lane]);
    float pd = wave_sum(v * a_d[h * HID + lane]);
    if (lane == 0) { al_s[node * NH + h] = ps; al_d[node * NH + h] = pd; }
  }
}

// ---------------- aggregation: one wave per destination node, online softmax ----------------
template <bool FINAL>
__global__ __launch_bounds__(256) void agg_kernel(const float* __restrict__ hfeat,
                                                  const float* __restrict__ al_s, const float* __restrict__ al_d,
                                                  const int* __restrict__ offs, const int* __restrict__ csr_src,
                                                  const float* __restrict__ bias, float* __restrict__ out, int n) {
  int lane = threadIdx.x & 63;
  int node = blockIdx.x * 4 + (threadIdx.x >> 6);
  if (node >= n) return;
  float4 adv = *(const float4*)(al_d + (size_t)node * 4);
  float m0 = -1e30f, m1 = -1e30f, m2 = -1e30f, m3 = -1e30f;
  float d0 = 0.f, d1 = 0.f, d2 = 0.f, d3 = 0.f;
  float c0 = 0.f, c1 = 0.f, c2 = 0.f, c3 = 0.f;
  int s = offs[node], e = offs[node + 1];
  for (int i = s; i < e; ++i) {
    int src = csr_src[i];
    float4 asv = *(const float4*)(al_s + (size_t)src * 4);
    const float* hp = hfeat + (size_t)src * NC + lane;
    float e0 = asv.x + adv.x; e0 = e0 >= 0.f ? e0 : NEG * e0;
    float e1 = asv.y + adv.y; e1 = e1 >= 0.f ? e1 : NEG * e1;
    float e2 = asv.z + adv.z; e2 = e2 >= 0.f ? e2 : NEG * e2;
    float e3 = asv.w + adv.w; e3 = e3 >= 0.f ? e3 : NEG * e3;
    float n0 = fmaxf(m0, e0), n1 = fmaxf(m1, e1), n2 = fmaxf(m2, e2), n3 = fmaxf(m3, e3);
    float f0 = __expf(m0 - n0), f1 = __expf(m1 - n1), f2 = __expf(m2 - n2), f3 = __expf(m3 - n3);
    float w0 = __expf(e0 - n0), w1 = __expf(e1 - n1), w2 = __expf(e2 - n2), w3 = __expf(e3 - n3);
    float h0 = hp[0], h1 = hp[64], h2 = hp[128], h3 = hp[192];
    c0 = c0 * f0 + w0 * h0;  d0 = d0 * f0 + w0;
    c1 = c1 * f1 + w1 * h1;  d1 = d1 * f1 + w1;
    c2 = c2 * f2 + w2 * h2;  d2 = d2 * f2 + w2;
    c3 = c3 * f3 + w3 * h3;  d3 = d3 * f3 + w3;
    m0 = n0; m1 = n1; m2 = n2; m3 = n3;
  }
  float val = 0.25f * (c0 / (d0 + 1e-16f) + c1 / (d1 + 1e-16f) +
                       c2 / (d2 + 1e-16f) + c3 / (d3 + 1e-16f)) + bias[lane];
  if (!FINAL) {
    out[(size_t)node * HID + lane] = fmaxf(val, 0.f);
  } else {
    float mx = val;
#pragma unroll
    for (int o = 32; o >= 1; o >>= 1) mx = fmaxf(mx, __shfl_xor(mx, o));
    float ex = __expf(val - mx);
    float sm = ex;
#pragma unroll
    for (int o = 32; o >= 1; o >>= 1) sm += __shfl_xor(sm, o);
    out[(size_t)node * HID + lane] = (val - mx) - logf(sm);
  }
}

// ---------------- launch ----------------
extern "C" void kernel_launch(void* const* d_in, const int* in_sizes, int n_in,
                              void* d_out, int out_size, void* d_ws, size_t ws_size,
                              hipStream_t stream) {
  const float* x   = (const float*)d_in[0];
  const int*   ei  = (const int*)d_in[1];   // int32 (JAX x64 disabled canonicalizes int64)
  const float* W1  = (const float*)d_in[2];
  const float* as1 = (const float*)d_in[3];
  const float* ad1 = (const float*)d_in[4];
  const float* b1  = (const float*)d_in[5];
  const float* W2  = (const float*)d_in[6];
  const float* as2 = (const float*)d_in[7];
  const float* ad2 = (const float*)d_in[8];
  const float* b2  = (const float*)d_in[9];
  float* out = (float*)d_out;

  const int N = NNODE;
  const int E = in_sizes[1] / 2;

  char* base = (char*)d_ws;
  size_t off = 0;
  auto alloc = [&](size_t bytes) -> void* {
    void* p = base + off;
    off += (bytes + 255) & ~(size_t)255;
    return p;
  };
  float* hfeat  = (float*)alloc((size_t)N * NC * 4);   // 51.2 MB, reused by both layers
  float* al_s   = (float*)alloc((size_t)N * NH * 4);
  float* al_d   = (float*)alloc((size_t)N * NH * 4);
  float* h1     = (float*)alloc((size_t)N * HID * 4);  // layer-1 output (relu'd)
  int*   deg    = (int*)alloc((size_t)N * 4);
  int*   offs   = (int*)alloc((size_t)(N + 1) * 4);
  int*   cursor = (int*)alloc((size_t)N * 4);
  int*   csr    = (int*)alloc((size_t)E * 4);

  const int nodeBlocks = (N + 3) / 4;           // 12500, wave per node
  const int edgeBlocks = (E + 255) / 256;       // 3125
  dim3 gemmGrid(NC / BN, (N + BM - 1) / BM);    // (4, 782)

  // --- CSR build (shared by both layers) ---
  zero_i32<<<(N + 255) / 256, 256, 0, stream>>>(deg, N);
  count_deg<<<edgeBlocks, 256, 0, stream>>>(ei, deg, E);
  scan_deg<<<1, 1024, 0, stream>>>(deg, offs, cursor, N);
  scatter_edges<<<edgeBlocks, 256, 0, stream>>>(ei, cursor, csr, E);

  // --- layer 1 ---
  gemm_kernel<<<gemmGrid, 256, 0, stream>>>(x, W1, hfeat, N, FIN);
  alpha_kernel<<<nodeBlocks, 256, 0, stream>>>(hfeat, as1, ad1, al_s, al_d, N);
  agg_kernel<false><<<nodeBlocks, 256, 0, stream>>>(hfeat, al_s, al_d, offs, csr, b1, h1, N);

  // --- layer 2 ---
  gemm_kernel<<<gemmGrid, 256, 0, stream>>>(h1, W2, hfeat, N, HID);
  alpha_kernel<<<nodeBlocks, 256, 0, stream>>>(hfeat, as2, ad2, al_s, al_d, N);
  agg_kernel<true><<<nodeBlocks, 256, 0, stream>>>(hfeat, al_s, al_d, offs, csr, b2, out, N);
}

// Round 2
// 578.661 us; speedup vs baseline: 1.1933x; 1.1933x over previous
//
#include <hip/hip_runtime.h>
#include <math.h>

// Problem constants (GATModel: N=50000, E=800000, F_IN=128, HID=OUT=64, H=4)
constexpr int NNODE = 50000;
constexpr int FIN   = 128;
constexpr int HID   = 64;
constexpr int NH    = 4;
constexpr int NC    = 256;   // NH * HID
constexpr float NEG = 0.2f;

typedef unsigned short u16;

__device__ __forceinline__ u16 f2bf(float f) {  // round-to-nearest-even
  unsigned int u = __float_as_uint(f);
  return (u16)((u + 0x7FFF + ((u >> 16) & 1)) >> 16);
}
__device__ __forceinline__ float bf2f(u16 h) {
  return __uint_as_float(((unsigned int)h) << 16);
}

// ---------------- utility ----------------
__global__ __launch_bounds__(256) void zero_i32(int* __restrict__ p, int n) {
  int i = blockIdx.x * 256 + threadIdx.x;
  if (i < n) p[i] = 0;
}

// ---------------- CSR build (by destination) ----------------
__global__ __launch_bounds__(256) void count_deg(const int* __restrict__ ei, int* __restrict__ deg, int E) {
  int i = blockIdx.x * 256 + threadIdx.x;
  if (i < E) atomicAdd(&deg[ei[E + i]], 1);
}

__global__ __launch_bounds__(1024) void scan_deg(const int* __restrict__ deg, int* __restrict__ offs,
                                                 int* __restrict__ cursor, int n) {
  __shared__ int sd[1024];
  int tid = threadIdx.x;
  const int CH = (NNODE + 1023) / 1024;  // 49
  int base = tid * CH;
  int s = 0;
  for (int i = 0; i < CH; ++i) { int idx = base + i; if (idx < n) s += deg[idx]; }
  sd[tid] = s;
  __syncthreads();
  for (int o = 1; o < 1024; o <<= 1) {
    int v = (tid >= o) ? sd[tid - o] : 0;
    __syncthreads();
    sd[tid] += v;
    __syncthreads();
  }
  int run = sd[tid] - s;  // exclusive prefix
  for (int i = 0; i < CH; ++i) {
    int idx = base + i;
    if (idx < n) { offs[idx] = run; cursor[idx] = run; run += deg[idx]; }
  }
  if (tid == 1023) offs[n] = sd[1023];
}

__global__ __launch_bounds__(256) void scatter_edges(const int* __restrict__ ei, int* __restrict__ cursor,
                                                     int* __restrict__ csr_src, int E) {
  int i = blockIdx.x * 256 + threadIdx.x;
  if (i < E) {
    int dst = ei[E + i];
    int pos = atomicAdd(&cursor[dst], 1);
    csr_src[pos] = ei[i];
  }
}

// ---------------- fused GEMM + alpha halves + bf16 pack ----------------
// C_raw[M,256] = A[M,K] @ B[K,256]; per (row, head): al_s = C_row_head . a_s[head],
// al_d likewise; bf16 copy stored packed as hf16[node][c][h] (c=0..63, h=0..3).
// One col-block (BN=64) == exactly one head.
#define BM 64
#define BN 64
#define BKK 32
__global__ __launch_bounds__(256) void gemm_alpha_kernel(
    const float* __restrict__ A, const float* __restrict__ B,
    const float* __restrict__ a_s, const float* __restrict__ a_d,
    u16* __restrict__ hf16, float* __restrict__ al_s, float* __restrict__ al_d,
    int M, int K) {
  __shared__ float As[BKK][BM + 4];  // stride 68 floats = 272 B: 16B-aligned rows, b128-friendly
  __shared__ float Bs[BKK][BN];
  int tid = threadIdx.x;
  int head = blockIdx.x;
  int row0 = blockIdx.y * BM;
  int col0 = head * BN;
  int tx = tid & 15, ty = tid >> 4;
  float acc[4][4] = {};
  for (int k0 = 0; k0 < K; k0 += BKK) {
#pragma unroll
    for (int p = 0; p < 2; ++p) {  // A tile: 64 rows x 32 k (transposed into LDS)
      int r = p * 32 + (tid >> 3);
      int kk = (tid & 7) * 4;
      float4 v = make_float4(0.f, 0.f, 0.f, 0.f);
      int gr = row0 + r;
      if (gr < M) v = *(const float4*)(A + (size_t)gr * K + k0 + kk);
      As[kk + 0][r] = v.x; As[kk + 1][r] = v.y; As[kk + 2][r] = v.z; As[kk + 3][r] = v.w;
    }
#pragma unroll
    for (int p = 0; p < 2; ++p) {  // B tile: 32 k x 64 cols
      int kk = p * 16 + (tid >> 4);
      int c = (tid & 15) * 4;
      *(float4*)(&Bs[kk][c]) = *(const float4*)(B + (size_t)(k0 + kk) * NC + col0 + c);
    }
    __syncthreads();
#pragma unroll
    for (int k = 0; k < BKK; ++k) {
      float4 av = *(const float4*)(&As[k][ty * 4]);  // ds_read_b128, 16-lane broadcast
      float4 bv = *(const float4*)(&Bs[k][tx * 4]);  // ds_read_b128, 2-way (free)
      float a[4] = {av.x, av.y, av.z, av.w};
      float b[4] = {bv.x, bv.y, bv.z, bv.w};
#pragma unroll
      for (int i = 0; i < 4; ++i)
#pragma unroll
        for (int j = 0; j < 4; ++j) acc[i][j] += a[i] * b[j];
    }
    __syncthreads();
  }
  // ---- epilogue: alpha halves + packed bf16 store ----
  const float* asp = a_s + head * HID + tx * 4;
  const float* adp = a_d + head * HID + tx * 4;
  float s0 = asp[0], s1 = asp[1], s2 = asp[2], s3 = asp[3];
  float t0 = adp[0], t1 = adp[1], t2 = adp[2], t3 = adp[3];
#pragma unroll
  for (int i = 0; i < 4; ++i) {
    int gr = row0 + ty * 4 + i;
    float ps = acc[i][0] * s0 + acc[i][1] * s1 + acc[i][2] * s2 + acc[i][3] * s3;
    float pd = acc[i][0] * t0 + acc[i][1] * t1 + acc[i][2] * t2 + acc[i][3] * t3;
#pragma unroll
    for (int o = 1; o < 16; o <<= 1) { ps += __shfl_xor(ps, o); pd += __shfl_xor(pd, o); }
    if (gr < M) {
      if (tx == 0) { al_s[gr * NH + head] = ps; al_d[gr * NH + head] = pd; }
      u16* hp = hf16 + (size_t)gr * NC + head;  // layout [node][c][h]
#pragma unroll
      for (int j = 0; j < 4; ++j) hp[(tx * 4 + j) * NH] = f2bf(acc[i][j]);
    }
  }
}

// ---------------- aggregation: one wave per destination node ----------------
// Plain exp (no max subtraction): logits are bounded ~|e|<20, exp(e)/sum(exp(e))
// is mathematically identical to the reference's max-shifted softmax and fp32-safe.
template <bool FINAL>
__global__ __launch_bounds__(256) void agg_kernel(const u16* __restrict__ hf16,
                                                  const float* __restrict__ al_s, const float* __restrict__ al_d,
                                                  const int* __restrict__ offs, const int* __restrict__ csr_src,
                                                  const float* __restrict__ bias, float* __restrict__ out, int n) {
  int lane = threadIdx.x & 63;
  int node = blockIdx.x * 4 + (threadIdx.x >> 6);
  if (node >= n) return;
  float4 ad = *(const float4*)(al_d + (size_t)node * NH);
  float c0 = 0.f, c1 = 0.f, c2 = 0.f, c3 = 0.f;
  float d0 = 0.f, d1 = 0.f, d2 = 0.f, d3 = 0.f;
  int s = offs[node], e = offs[node + 1];
  int i = s;
  for (; i + 2 <= e; i += 2) {
    int sa = csr_src[i], sb = csr_src[i + 1];
    float4 aa = *(const float4*)(al_s + (size_t)sa * NH);
    float4 ab = *(const float4*)(al_s + (size_t)sb * NH);
    ushort4 ha = ((const ushort4*)(hf16 + (size_t)sa * NC))[lane];  // all 4 heads, one req
    ushort4 hb = ((const ushort4*)(hf16 + (size_t)sb * NC))[lane];
    float e0, w0;
    e0 = aa.x + ad.x; e0 = e0 >= 0.f ? e0 : NEG * e0; w0 = __expf(e0); c0 += w0 * bf2f(ha.x); d0 += w0;
    e0 = aa.y + ad.y; e0 = e0 >= 0.f ? e0 : NEG * e0; w0 = __expf(e0); c1 += w0 * bf2f(ha.y); d1 += w0;
    e0 = aa.z + ad.z; e0 = e0 >= 0.f ? e0 : NEG * e0; w0 = __expf(e0); c2 += w0 * bf2f(ha.z); d2 += w0;
    e0 = aa.w + ad.w; e0 = e0 >= 0.f ? e0 : NEG * e0; w0 = __expf(e0); c3 += w0 * bf2f(ha.w); d3 += w0;
    e0 = ab.x + ad.x; e0 = e0 >= 0.f ? e0 : NEG * e0; w0 = __expf(e0); c0 += w0 * bf2f(hb.x); d0 += w0;
    e0 = ab.y + ad.y; e0 = e0 >= 0.f ? e0 : NEG * e0; w0 = __expf(e0); c1 += w0 * bf2f(hb.y); d1 += w0;
    e0 = ab.z + ad.z; e0 = e0 >= 0.f ? e0 : NEG * e0; w0 = __expf(e0); c2 += w0 * bf2f(hb.z); d2 += w0;
    e0 = ab.w + ad.w; e0 = e0 >= 0.f ? e0 : NEG * e0; w0 = __expf(e0); c3 += w0 * bf2f(hb.w); d3 += w0;
  }
  if (i < e) {
    int sa = csr_src[i];
    float4 aa = *(const float4*)(al_s + (size_t)sa * NH);
    ushort4 ha = ((const ushort4*)(hf16 + (size_t)sa * NC))[lane];
    float e0, w0;
    e0 = aa.x + ad.x; e0 = e0 >= 0.f ? e0 : NEG * e0; w0 = __expf(e0); c0 += w0 * bf2f(ha.x); d0 += w0;
    e0 = aa.y + ad.y; e0 = e0 >= 0.f ? e0 : NEG * e0; w0 = __expf(e0); c1 += w0 * bf2f(ha.y); d1 += w0;
    e0 = aa.z + ad.z; e0 = e0 >= 0.f ? e0 : NEG * e0; w0 = __expf(e0); c2 += w0 * bf2f(ha.z); d2 += w0;
    e0 = aa.w + ad.w; e0 = e0 >= 0.f ? e0 : NEG * e0; w0 = __expf(e0); c3 += w0 * bf2f(ha.w); d3 += w0;
  }
  float val = 0.25f * (c0 / (d0 + 1e-16f) + c1 / (d1 + 1e-16f) +
                       c2 / (d2 + 1e-16f) + c3 / (d3 + 1e-16f)) + bias[lane];
  if (!FINAL) {
    out[(size_t)node * HID + lane] = fmaxf(val, 0.f);
  } else {
    float mx = val;
#pragma unroll
    for (int o = 32; o >= 1; o >>= 1) mx = fmaxf(mx, __shfl_xor(mx, o));
    float ex = __expf(val - mx);
    float sm = ex;
#pragma unroll
    for (int o = 32; o >= 1; o >>= 1) sm += __shfl_xor(sm, o);
    out[(size_t)node * HID + lane] = (val - mx) - logf(sm);
  }
}

// ---------------- launch ----------------
extern "C" void kernel_launch(void* const* d_in, const int* in_sizes, int n_in,
                              void* d_out, int out_size, void* d_ws, size_t ws_size,
                              hipStream_t stream) {
  const float* x   = (const float*)d_in[0];
  const int*   ei  = (const int*)d_in[1];   // int32 (JAX x64 disabled canonicalizes int64)
  const float* W1  = (const float*)d_in[2];
  const float* as1 = (const float*)d_in[3];
  const float* ad1 = (const float*)d_in[4];
  const float* b1  = (const float*)d_in[5];
  const float* W2  = (const float*)d_in[6];
  const float* as2 = (const float*)d_in[7];
  const float* ad2 = (const float*)d_in[8];
  const float* b2  = (const float*)d_in[9];
  float* out = (float*)d_out;

  const int N = NNODE;
  const int E = in_sizes[1] / 2;

  char* base = (char*)d_ws;
  size_t off = 0;
  auto alloc = [&](size_t bytes) -> void* {
    void* p = base + off;
    off += (bytes + 255) & ~(size_t)255;
    return p;
  };
  u16*   hf16   = (u16*)alloc((size_t)N * NC * 2);     // 25.6 MB packed [node][c][h]
  float* al_s   = (float*)alloc((size_t)N * NH * 4);
  float* al_d   = (float*)alloc((size_t)N * NH * 4);
  float* h1     = (float*)alloc((size_t)N * HID * 4);  // layer-1 output (relu'd)
  int*   deg    = (int*)alloc((size_t)N * 4);
  int*   offs   = (int*)alloc((size_t)(N + 1) * 4);
  int*   cursor = (int*)alloc((size_t)N * 4);
  int*   csr    = (int*)alloc((size_t)E * 4);

  const int nodeBlocks = (N + 3) / 4;           // 12500, wave per node
  const int edgeBlocks = (E + 255) / 256;       // 3125
  dim3 gemmGrid(NC / BN, (N + BM - 1) / BM);    // (4, 782)

  // --- CSR build (shared by both layers) ---
  zero_i32<<<(N + 255) / 256, 256, 0, stream>>>(deg, N);
  count_deg<<<edgeBlocks, 256, 0, stream>>>(ei, deg, E);
  scan_deg<<<1, 1024, 0, stream>>>(deg, offs, cursor, N);
  scatter_edges<<<edgeBlocks, 256, 0, stream>>>(ei, cursor, csr, E);

  // --- layer 1 ---
  gemm_alpha_kernel<<<gemmGrid, 256, 0, stream>>>(x, W1, as1, ad1, hf16, al_s, al_d, N, FIN);
  agg_kernel<false><<<nodeBlocks, 256, 0, stream>>>(hf16, al_s, al_d, offs, csr, b1, h1, N);

  // --- layer 2 ---
  gemm_alpha_kernel<<<gemmGrid, 256, 0, stream>>>(h1, W2, as2, ad2, hf16, al_s, al_d, N, HID);
  agg_kernel<true><<<nodeBlocks, 256, 0, stream>>>(hf16, al_s, al_d, offs, csr, b2, out, N);
}

// Round 3
// 457.936 us; speedup vs baseline: 1.5078x; 1.2636x over previous
//
#include <hip/hip_runtime.h>
#include <math.h>

// Problem constants (GATModel: N=50000, E=800000, F_IN=128, HID=OUT=64, H=4)
constexpr int NNODE = 50000;
constexpr int FIN   = 128;
constexpr int HID   = 64;
constexpr int NH    = 4;
constexpr int NC    = 256;   // NH * HID
constexpr float NEG = 0.2f;

typedef unsigned short u16;

__device__ __forceinline__ u16 f2bf(float f) {  // round-to-nearest-even
  unsigned int u = __float_as_uint(f);
  return (u16)((u + 0x7FFF + ((u >> 16) & 1)) >> 16);
}
__device__ __forceinline__ float bf2f(u16 h) {
  return __uint_as_float(((unsigned int)h) << 16);
}

// ---------------- utility ----------------
__global__ __launch_bounds__(256) void zero_i32(int* __restrict__ p, int n) {
  int i = blockIdx.x * 256 + threadIdx.x;
  if (i < n) p[i] = 0;
}

// ---------------- CSR build (by destination) ----------------
__global__ __launch_bounds__(256) void count_deg(const int* __restrict__ ei, int* __restrict__ deg, int E) {
  int i = blockIdx.x * 256 + threadIdx.x;
  if (i < E) atomicAdd(&deg[ei[E + i]], 1);
}

// 3-phase hierarchical exclusive scan over deg[N] (N=50000 -> 196 blocks).
// Phase 1: per-block sums. Phase 2: one tiny block scans the 196 sums.
// Phase 3: per-block exclusive scan + block offset -> offs/cursor.
__global__ __launch_bounds__(256) void scan_phase1(const int* __restrict__ deg,
                                                   int* __restrict__ blockSums, int n) {
  __shared__ int sm[256];
  int tid = threadIdx.x;
  int i = blockIdx.x * 256 + tid;
  sm[tid] = (i < n) ? deg[i] : 0;
  __syncthreads();
#pragma unroll
  for (int o = 128; o > 0; o >>= 1) {
    if (tid < o) sm[tid] += sm[tid + o];
    __syncthreads();
  }
  if (tid == 0) blockSums[blockIdx.x] = sm[0];
}

__global__ __launch_bounds__(256) void scan_phase2(const int* __restrict__ blockSums,
                                                   int* __restrict__ blockOffs, int nb,
                                                   int* __restrict__ total_out) {
  __shared__ int sm[256];
  int tid = threadIdx.x;
  int v = (tid < nb) ? blockSums[tid] : 0;
  sm[tid] = v;
  __syncthreads();
#pragma unroll
  for (int o = 1; o < 256; o <<= 1) {
    int t = (tid >= o) ? sm[tid - o] : 0;
    __syncthreads();
    sm[tid] += t;
    __syncthreads();
  }
  if (tid < nb) blockOffs[tid] = sm[tid] - v;  // exclusive
  if (tid == 255) *total_out = sm[255];        // offs[N] = E
}

__global__ __launch_bounds__(256) void scan_phase3(const int* __restrict__ deg,
                                                   const int* __restrict__ blockOffs,
                                                   int* __restrict__ offs, int* __restrict__ cursor, int n) {
  __shared__ int sm[256];
  int tid = threadIdx.x;
  int i = blockIdx.x * 256 + tid;
  int v = (i < n) ? deg[i] : 0;
  sm[tid] = v;
  __syncthreads();
#pragma unroll
  for (int o = 1; o < 256; o <<= 1) {
    int t = (tid >= o) ? sm[tid - o] : 0;
    __syncthreads();
    sm[tid] += t;
    __syncthreads();
  }
  int ex = sm[tid] - v + blockOffs[blockIdx.x];
  if (i < n) { offs[i] = ex; cursor[i] = ex; }
}

__global__ __launch_bounds__(256) void scatter_edges(const int* __restrict__ ei, int* __restrict__ cursor,
                                                     int* __restrict__ csr_src, int E) {
  int i = blockIdx.x * 256 + threadIdx.x;
  if (i < E) {
    int dst = ei[E + i];
    int pos = atomicAdd(&cursor[dst], 1);
    csr_src[pos] = ei[i];
  }
}

// ---------------- fused GEMM + alpha halves + bf16 pack ----------------
// C_raw[M,256] = A[M,K] @ B[K,256]; per (row, head): al_s = C_row_head . a_s[head],
// al_d likewise; bf16 copy stored packed as hf16[node][c][h] (c=0..63, h=0..3).
// One col-block (BN=64) == exactly one head.
#define BM 64
#define BN 64
#define BKK 32
__global__ __launch_bounds__(256) void gemm_alpha_kernel(
    const float* __restrict__ A, const float* __restrict__ B,
    const float* __restrict__ a_s, const float* __restrict__ a_d,
    u16* __restrict__ hf16, float* __restrict__ al_s, float* __restrict__ al_d,
    int M, int K) {
  __shared__ float As[BKK][BM + 4];  // stride 68 floats = 272 B: 16B-aligned rows, b128-friendly
  __shared__ float Bs[BKK][BN];
  int tid = threadIdx.x;
  int head = blockIdx.x;
  int row0 = blockIdx.y * BM;
  int col0 = head * BN;
  int tx = tid & 15, ty = tid >> 4;
  float acc[4][4] = {};
  for (int k0 = 0; k0 < K; k0 += BKK) {
#pragma unroll
    for (int p = 0; p < 2; ++p) {  // A tile: 64 rows x 32 k (transposed into LDS)
      int r = p * 32 + (tid >> 3);
      int kk = (tid & 7) * 4;
      float4 v = make_float4(0.f, 0.f, 0.f, 0.f);
      int gr = row0 + r;
      if (gr < M) v = *(const float4*)(A + (size_t)gr * K + k0 + kk);
      As[kk + 0][r] = v.x; As[kk + 1][r] = v.y; As[kk + 2][r] = v.z; As[kk + 3][r] = v.w;
    }
#pragma unroll
    for (int p = 0; p < 2; ++p) {  // B tile: 32 k x 64 cols
      int kk = p * 16 + (tid >> 4);
      int c = (tid & 15) * 4;
      *(float4*)(&Bs[kk][c]) = *(const float4*)(B + (size_t)(k0 + kk) * NC + col0 + c);
    }
    __syncthreads();
#pragma unroll
    for (int k = 0; k < BKK; ++k) {
      float4 av = *(const float4*)(&As[k][ty * 4]);  // ds_read_b128, 16-lane broadcast
      float4 bv = *(const float4*)(&Bs[k][tx * 4]);  // ds_read_b128, 2-way (free)
      float a[4] = {av.x, av.y, av.z, av.w};
      float b[4] = {bv.x, bv.y, bv.z, bv.w};
#pragma unroll
      for (int i = 0; i < 4; ++i)
#pragma unroll
        for (int j = 0; j < 4; ++j) acc[i][j] += a[i] * b[j];
    }
    __syncthreads();
  }
  // ---- epilogue: alpha halves + packed bf16 store ----
  const float* asp = a_s + head * HID + tx * 4;
  const float* adp = a_d + head * HID + tx * 4;
  float s0 = asp[0], s1 = asp[1], s2 = asp[2], s3 = asp[3];
  float t0 = adp[0], t1 = adp[1], t2 = adp[2], t3 = adp[3];
#pragma unroll
  for (int i = 0; i < 4; ++i) {
    int gr = row0 + ty * 4 + i;
    float ps = acc[i][0] * s0 + acc[i][1] * s1 + acc[i][2] * s2 + acc[i][3] * s3;
    float pd = acc[i][0] * t0 + acc[i][1] * t1 + acc[i][2] * t2 + acc[i][3] * t3;
#pragma unroll
    for (int o = 1; o < 16; o <<= 1) { ps += __shfl_xor(ps, o); pd += __shfl_xor(pd, o); }
    if (gr < M) {
      if (tx == 0) { al_s[gr * NH + head] = ps; al_d[gr * NH + head] = pd; }
      u16* hp = hf16 + (size_t)gr * NC + head;  // layout [node][c][h]
#pragma unroll
      for (int j = 0; j < 4; ++j) hp[(tx * 4 + j) * NH] = f2bf(acc[i][j]);
    }
  }
}

// ---------------- aggregation: one wave per destination node ----------------
// Plain exp (no max subtraction): logits are bounded ~|e|<20, exp(e)/sum(exp(e))
// is mathematically identical to the reference's max-shifted softmax and fp32-safe.
template <bool FINAL>
__global__ __launch_bounds__(256) void agg_kernel(const u16* __restrict__ hf16,
                                                  const float* __restrict__ al_s, const float* __restrict__ al_d,
                                                  const int* __restrict__ offs, const int* __restrict__ csr_src,
                                                  const float* __restrict__ bias, float* __restrict__ out, int n) {
  int lane = threadIdx.x & 63;
  int node = blockIdx.x * 4 + (threadIdx.x >> 6);
  if (node >= n) return;
  float4 ad = *(const float4*)(al_d + (size_t)node * NH);
  float c0 = 0.f, c1 = 0.f, c2 = 0.f, c3 = 0.f;
  float d0 = 0.f, d1 = 0.f, d2 = 0.f, d3 = 0.f;
  int s = offs[node], e = offs[node + 1];
  int i = s;
  for (; i + 2 <= e; i += 2) {
    int sa = csr_src[i], sb = csr_src[i + 1];
    float4 aa = *(const float4*)(al_s + (size_t)sa * NH);
    float4 ab = *(const float4*)(al_s + (size_t)sb * NH);
    ushort4 ha = ((const ushort4*)(hf16 + (size_t)sa * NC))[lane];  // all 4 heads, one req
    ushort4 hb = ((const ushort4*)(hf16 + (size_t)sb * NC))[lane];
    float e0, w0;
    e0 = aa.x + ad.x; e0 = e0 >= 0.f ? e0 : NEG * e0; w0 = __expf(e0); c0 += w0 * bf2f(ha.x); d0 += w0;
    e0 = aa.y + ad.y; e0 = e0 >= 0.f ? e0 : NEG * e0; w0 = __expf(e0); c1 += w0 * bf2f(ha.y); d1 += w0;
    e0 = aa.z + ad.z; e0 = e0 >= 0.f ? e0 : NEG * e0; w0 = __expf(e0); c2 += w0 * bf2f(ha.z); d2 += w0;
    e0 = aa.w + ad.w; e0 = e0 >= 0.f ? e0 : NEG * e0; w0 = __expf(e0); c3 += w0 * bf2f(ha.w); d3 += w0;
    e0 = ab.x + ad.x; e0 = e0 >= 0.f ? e0 : NEG * e0; w0 = __expf(e0); c0 += w0 * bf2f(hb.x); d0 += w0;
    e0 = ab.y + ad.y; e0 = e0 >= 0.f ? e0 : NEG * e0; w0 = __expf(e0); c1 += w0 * bf2f(hb.y); d1 += w0;
    e0 = ab.z + ad.z; e0 = e0 >= 0.f ? e0 : NEG * e0; w0 = __expf(e0); c2 += w0 * bf2f(hb.z); d2 += w0;
    e0 = ab.w + ad.w; e0 = e0 >= 0.f ? e0 : NEG * e0; w0 = __expf(e0); c3 += w0 * bf2f(hb.w); d3 += w0;
  }
  if (i < e) {
    int sa = csr_src[i];
    float4 aa = *(const float4*)(al_s + (size_t)sa * NH);
    ushort4 ha = ((const ushort4*)(hf16 + (size_t)sa * NC))[lane];
    float e0, w0;
    e0 = aa.x + ad.x; e0 = e0 >= 0.f ? e0 : NEG * e0; w0 = __expf(e0); c0 += w0 * bf2f(ha.x); d0 += w0;
    e0 = aa.y + ad.y; e0 = e0 >= 0.f ? e0 : NEG * e0; w0 = __expf(e0); c1 += w0 * bf2f(ha.y); d1 += w0;
    e0 = aa.z + ad.z; e0 = e0 >= 0.f ? e0 : NEG * e0; w0 = __expf(e0); c2 += w0 * bf2f(ha.z); d2 += w0;
    e0 = aa.w + ad.w; e0 = e0 >= 0.f ? e0 : NEG * e0; w0 = __expf(e0); c3 += w0 * bf2f(ha.w); d3 += w0;
  }
  float val = 0.25f * (c0 / (d0 + 1e-16f) + c1 / (d1 + 1e-16f) +
                       c2 / (d2 + 1e-16f) + c3 / (d3 + 1e-16f)) + bias[lane];
  if (!FINAL) {
    out[(size_t)node * HID + lane] = fmaxf(val, 0.f);
  } else {
    float mx = val;
#pragma unroll
    for (int o = 32; o >= 1; o >>= 1) mx = fmaxf(mx, __shfl_xor(mx, o));
    float ex = __expf(val - mx);
    float sm = ex;
#pragma unroll
    for (int o = 32; o >= 1; o >>= 1) sm += __shfl_xor(sm, o);
    out[(size_t)node * HID + lane] = (val - mx) - logf(sm);
  }
}

// ---------------- launch ----------------
extern "C" void kernel_launch(void* const* d_in, const int* in_sizes, int n_in,
                              void* d_out, int out_size, void* d_ws, size_t ws_size,
                              hipStream_t stream) {
  const float* x   = (const float*)d_in[0];
  const int*   ei  = (const int*)d_in[1];   // int32 (JAX x64 disabled canonicalizes int64)
  const float* W1  = (const float*)d_in[2];
  const float* as1 = (const float*)d_in[3];
  const float* ad1 = (const float*)d_in[4];
  const float* b1  = (const float*)d_in[5];
  const float* W2  = (const float*)d_in[6];
  const float* as2 = (const float*)d_in[7];
  const float* ad2 = (const float*)d_in[8];
  const float* b2  = (const float*)d_in[9];
  float* out = (float*)d_out;

  const int N = NNODE;
  const int E = in_sizes[1] / 2;

  char* base = (char*)d_ws;
  size_t off = 0;
  auto alloc = [&](size_t bytes) -> void* {
    void* p = base + off;
    off += (bytes + 255) & ~(size_t)255;
    return p;
  };
  u16*   hf16   = (u16*)alloc((size_t)N * NC * 2);     // 25.6 MB packed [node][c][h]
  float* al_s   = (float*)alloc((size_t)N * NH * 4);
  float* al_d   = (float*)alloc((size_t)N * NH * 4);
  float* h1     = (float*)alloc((size_t)N * HID * 4);  // layer-1 output (relu'd)
  int*   deg    = (int*)alloc((size_t)N * 4);
  int*   offs   = (int*)alloc((size_t)(N + 1) * 4);
  int*   cursor = (int*)alloc((size_t)N * 4);
  int*   csr    = (int*)alloc((size_t)E * 4);
  int*   bsums  = (int*)alloc(256 * 4);
  int*   boffs  = (int*)alloc(256 * 4);

  const int nodeBlocks = (N + 3) / 4;           // 12500, wave per node
  const int edgeBlocks = (E + 255) / 256;       // 3125
  const int scanBlocks = (N + 255) / 256;       // 196
  dim3 gemmGrid(NC / BN, (N + BM - 1) / BM);    // (4, 782)

  // --- CSR build (shared by both layers) ---
  zero_i32<<<(N + 255) / 256, 256, 0, stream>>>(deg, N);
  count_deg<<<edgeBlocks, 256, 0, stream>>>(ei, deg, E);
  scan_phase1<<<scanBlocks, 256, 0, stream>>>(deg, bsums, N);
  scan_phase2<<<1, 256, 0, stream>>>(bsums, boffs, scanBlocks, offs + N);
  scan_phase3<<<scanBlocks, 256, 0, stream>>>(deg, boffs, offs, cursor, N);
  scatter_edges<<<edgeBlocks, 256, 0, stream>>>(ei, cursor, csr, E);

  // --- layer 1 ---
  gemm_alpha_kernel<<<gemmGrid, 256, 0, stream>>>(x, W1, as1, ad1, hf16, al_s, al_d, N, FIN);
  agg_kernel<false><<<nodeBlocks, 256, 0, stream>>>(hf16, al_s, al_d, offs, csr, b1, h1, N);

  // --- layer 2 ---
  gemm_alpha_kernel<<<gemmGrid, 256, 0, stream>>>(h1, W2, as2, ad2, hf16, al_s, al_d, N, HID);
  agg_kernel<true><<<nodeBlocks, 256, 0, stream>>>(hf16, al_s, al_d, offs, csr, b2, out, N);
}

// Round 4
// 451.552 us; speedup vs baseline: 1.5292x; 1.0141x over previous
//
#include <hip/hip_runtime.h>
#include <math.h>

// Problem constants (GATModel: N=50000, E=800000, F_IN=128, HID=OUT=64, H=4)
constexpr int NNODE = 50000;
constexpr int FIN   = 128;
constexpr int HID   = 64;
constexpr int NH    = 4;
constexpr int NC    = 256;   // NH * HID
constexpr float NEG = 0.2f;

typedef unsigned short u16;

__device__ __forceinline__ u16 f2bf(float f) {  // round-to-nearest-even
  unsigned int u = __float_as_uint(f);
  return (u16)((u + 0x7FFF + ((u >> 16) & 1)) >> 16);
}
__device__ __forceinline__ float bf2f(u16 h) {
  return __uint_as_float(((unsigned int)h) << 16);
}

// ---------------- utility ----------------
__global__ __launch_bounds__(256) void zero_i32(int* __restrict__ p, int n) {
  int i = blockIdx.x * 256 + threadIdx.x;
  if (i < n) p[i] = 0;
}

// ---------------- CSR build (by destination) ----------------
__global__ __launch_bounds__(256) void count_deg(const int* __restrict__ ei, int* __restrict__ deg, int E) {
  int i = blockIdx.x * 256 + threadIdx.x;
  if (i < E) atomicAdd(&deg[ei[E + i]], 1);
}

// 3-phase hierarchical exclusive scan over deg[N] (N=50000 -> 196 blocks).
__global__ __launch_bounds__(256) void scan_phase1(const int* __restrict__ deg,
                                                   int* __restrict__ blockSums, int n) {
  __shared__ int sm[256];
  int tid = threadIdx.x;
  int i = blockIdx.x * 256 + tid;
  sm[tid] = (i < n) ? deg[i] : 0;
  __syncthreads();
#pragma unroll
  for (int o = 128; o > 0; o >>= 1) {
    if (tid < o) sm[tid] += sm[tid + o];
    __syncthreads();
  }
  if (tid == 0) blockSums[blockIdx.x] = sm[0];
}

__global__ __launch_bounds__(256) void scan_phase2(const int* __restrict__ blockSums,
                                                   int* __restrict__ blockOffs, int nb,
                                                   int* __restrict__ total_out) {
  __shared__ int sm[256];
  int tid = threadIdx.x;
  int v = (tid < nb) ? blockSums[tid] : 0;
  sm[tid] = v;
  __syncthreads();
#pragma unroll
  for (int o = 1; o < 256; o <<= 1) {
    int t = (tid >= o) ? sm[tid - o] : 0;
    __syncthreads();
    sm[tid] += t;
    __syncthreads();
  }
  if (tid < nb) blockOffs[tid] = sm[tid] - v;  // exclusive
  if (tid == 255) *total_out = sm[255];        // offs[N] = E
}

__global__ __launch_bounds__(256) void scan_phase3(const int* __restrict__ deg,
                                                   const int* __restrict__ blockOffs,
                                                   int* __restrict__ offs, int* __restrict__ cursor, int n) {
  __shared__ int sm[256];
  int tid = threadIdx.x;
  int i = blockIdx.x * 256 + tid;
  int v = (i < n) ? deg[i] : 0;
  sm[tid] = v;
  __syncthreads();
#pragma unroll
  for (int o = 1; o < 256; o <<= 1) {
    int t = (tid >= o) ? sm[tid - o] : 0;
    __syncthreads();
    sm[tid] += t;
    __syncthreads();
  }
  int ex = sm[tid] - v + blockOffs[blockIdx.x];
  if (i < n) { offs[i] = ex; cursor[i] = ex; }
}

__global__ __launch_bounds__(256) void scatter_edges(const int* __restrict__ ei, int* __restrict__ cursor,
                                                     int* __restrict__ csr_src, int* __restrict__ csr_dst, int E) {
  int i = blockIdx.x * 256 + threadIdx.x;
  if (i < E) {
    int dst = ei[E + i];
    int pos = atomicAdd(&cursor[dst], 1);
    csr_src[pos] = ei[i];
    csr_dst[pos] = dst;
  }
}

// ---------------- per-edge attention weights (hoisted out of agg) ----------------
// One thread per CSR slot: w_h = exp(leakyrelu(al_s[src][h] + al_d[dst][h])).
// Same math as before (no max-shift; logits bounded ~|e|<20, fp32-exp safe).
__global__ __launch_bounds__(256) void edge_weights(const int* __restrict__ csr_src,
                                                    const int* __restrict__ csr_dst,
                                                    const float* __restrict__ al_s,
                                                    const float* __restrict__ al_d,
                                                    float4* __restrict__ w, int E) {
  int i = blockIdx.x * 256 + threadIdx.x;
  if (i >= E) return;
  float4 a = ((const float4*)al_s)[csr_src[i]];
  float4 b = ((const float4*)al_d)[csr_dst[i]];
  float e0 = a.x + b.x; e0 = e0 >= 0.f ? e0 : NEG * e0;
  float e1 = a.y + b.y; e1 = e1 >= 0.f ? e1 : NEG * e1;
  float e2 = a.z + b.z; e2 = e2 >= 0.f ? e2 : NEG * e2;
  float e3 = a.w + b.w; e3 = e3 >= 0.f ? e3 : NEG * e3;
  w[i] = make_float4(__expf(e0), __expf(e1), __expf(e2), __expf(e3));
}

// ---------------- fused GEMM + alpha halves + bf16 pack ----------------
#define BM 64
#define BN 64
#define BKK 32
__global__ __launch_bounds__(256) void gemm_alpha_kernel(
    const float* __restrict__ A, const float* __restrict__ B,
    const float* __restrict__ a_s, const float* __restrict__ a_d,
    u16* __restrict__ hf16, float* __restrict__ al_s, float* __restrict__ al_d,
    int M, int K) {
  __shared__ float As[BKK][BM + 4];  // stride 68 floats: 16B-aligned rows, b128-friendly
  __shared__ float Bs[BKK][BN];
  int tid = threadIdx.x;
  int head = blockIdx.x;
  int row0 = blockIdx.y * BM;
  int col0 = head * BN;
  int tx = tid & 15, ty = tid >> 4;
  float acc[4][4] = {};
  for (int k0 = 0; k0 < K; k0 += BKK) {
#pragma unroll
    for (int p = 0; p < 2; ++p) {  // A tile: 64 rows x 32 k (transposed into LDS)
      int r = p * 32 + (tid >> 3);
      int kk = (tid & 7) * 4;
      float4 v = make_float4(0.f, 0.f, 0.f, 0.f);
      int gr = row0 + r;
      if (gr < M) v = *(const float4*)(A + (size_t)gr * K + k0 + kk);
      As[kk + 0][r] = v.x; As[kk + 1][r] = v.y; As[kk + 2][r] = v.z; As[kk + 3][r] = v.w;
    }
#pragma unroll
    for (int p = 0; p < 2; ++p) {  // B tile: 32 k x 64 cols
      int kk = p * 16 + (tid >> 4);
      int c = (tid & 15) * 4;
      *(float4*)(&Bs[kk][c]) = *(const float4*)(B + (size_t)(k0 + kk) * NC + col0 + c);
    }
    __syncthreads();
#pragma unroll
    for (int k = 0; k < BKK; ++k) {
      float4 av = *(const float4*)(&As[k][ty * 4]);  // ds_read_b128, 16-lane broadcast
      float4 bv = *(const float4*)(&Bs[k][tx * 4]);  // ds_read_b128, 2-way (free)
      float a[4] = {av.x, av.y, av.z, av.w};
      float b[4] = {bv.x, bv.y, bv.z, bv.w};
#pragma unroll
      for (int i = 0; i < 4; ++i)
#pragma unroll
        for (int j = 0; j < 4; ++j) acc[i][j] += a[i] * b[j];
    }
    __syncthreads();
  }
  // ---- epilogue: alpha halves + packed bf16 store ----
  const float* asp = a_s + head * HID + tx * 4;
  const float* adp = a_d + head * HID + tx * 4;
  float s0 = asp[0], s1 = asp[1], s2 = asp[2], s3 = asp[3];
  float t0 = adp[0], t1 = adp[1], t2 = adp[2], t3 = adp[3];
#pragma unroll
  for (int i = 0; i < 4; ++i) {
    int gr = row0 + ty * 4 + i;
    float ps = acc[i][0] * s0 + acc[i][1] * s1 + acc[i][2] * s2 + acc[i][3] * s3;
    float pd = acc[i][0] * t0 + acc[i][1] * t1 + acc[i][2] * t2 + acc[i][3] * t3;
#pragma unroll
    for (int o = 1; o < 16; o <<= 1) { ps += __shfl_xor(ps, o); pd += __shfl_xor(pd, o); }
    if (gr < M) {
      if (tx == 0) { al_s[gr * NH + head] = ps; al_d[gr * NH + head] = pd; }
      u16* hp = hf16 + (size_t)gr * NC + head;  // layout [node][c][h]
#pragma unroll
      for (int j = 0; j < 4; ++j) hp[(tx * 4 + j) * NH] = f2bf(acc[i][j]);
    }
  }
}

// ---------------- aggregation: one wave per destination node ----------------
// Weights precomputed per CSR slot; inner loop is pure gather + fma.
template <bool FINAL>
__global__ __launch_bounds__(256) void agg_kernel(const u16* __restrict__ hf16,
                                                  const float4* __restrict__ w,
                                                  const int* __restrict__ offs, const int* __restrict__ csr_src,
                                                  const float* __restrict__ bias, float* __restrict__ out, int n) {
  int lane = threadIdx.x & 63;
  int node = blockIdx.x * 4 + (threadIdx.x >> 6);
  if (node >= n) return;
  float c0 = 0.f, c1 = 0.f, c2 = 0.f, c3 = 0.f;
  float d0 = 0.f, d1 = 0.f, d2 = 0.f, d3 = 0.f;
  int s = offs[node], e = offs[node + 1];
  int i = s;
  for (; i + 2 <= e; i += 2) {
    int sa = csr_src[i], sb = csr_src[i + 1];
    float4 wa = w[i];
    float4 wb = w[i + 1];
    ushort4 ha = ((const ushort4*)(hf16 + (size_t)sa * NC))[lane];  // all 4 heads, one req
    ushort4 hb = ((const ushort4*)(hf16 + (size_t)sb * NC))[lane];
    c0 += wa.x * bf2f(ha.x); d0 += wa.x;
    c1 += wa.y * bf2f(ha.y); d1 += wa.y;
    c2 += wa.z * bf2f(ha.z); d2 += wa.z;
    c3 += wa.w * bf2f(ha.w); d3 += wa.w;
    c0 += wb.x * bf2f(hb.x); d0 += wb.x;
    c1 += wb.y * bf2f(hb.y); d1 += wb.y;
    c2 += wb.z * bf2f(hb.z); d2 += wb.z;
    c3 += wb.w * bf2f(hb.w); d3 += wb.w;
  }
  if (i < e) {
    int sa = csr_src[i];
    float4 wa = w[i];
    ushort4 ha = ((const ushort4*)(hf16 + (size_t)sa * NC))[lane];
    c0 += wa.x * bf2f(ha.x); d0 += wa.x;
    c1 += wa.y * bf2f(ha.y); d1 += wa.y;
    c2 += wa.z * bf2f(ha.z); d2 += wa.z;
    c3 += wa.w * bf2f(ha.w); d3 += wa.w;
  }
  float val = 0.25f * (c0 / (d0 + 1e-16f) + c1 / (d1 + 1e-16f) +
                       c2 / (d2 + 1e-16f) + c3 / (d3 + 1e-16f)) + bias[lane];
  if (!FINAL) {
    out[(size_t)node * HID + lane] = fmaxf(val, 0.f);
  } else {
    float mx = val;
#pragma unroll
    for (int o = 32; o >= 1; o >>= 1) mx = fmaxf(mx, __shfl_xor(mx, o));
    float ex = __expf(val - mx);
    float sm = ex;
#pragma unroll
    for (int o = 32; o >= 1; o >>= 1) sm += __shfl_xor(sm, o);
    out[(size_t)node * HID + lane] = (val - mx) - logf(sm);
  }
}

// ---------------- launch ----------------
extern "C" void kernel_launch(void* const* d_in, const int* in_sizes, int n_in,
                              void* d_out, int out_size, void* d_ws, size_t ws_size,
                              hipStream_t stream) {
  const float* x   = (const float*)d_in[0];
  const int*   ei  = (const int*)d_in[1];   // int32 (JAX x64 disabled canonicalizes int64)
  const float* W1  = (const float*)d_in[2];
  const float* as1 = (const float*)d_in[3];
  const float* ad1 = (const float*)d_in[4];
  const float* b1  = (const float*)d_in[5];
  const float* W2  = (const float*)d_in[6];
  const float* as2 = (const float*)d_in[7];
  const float* ad2 = (const float*)d_in[8];
  const float* b2  = (const float*)d_in[9];
  float* out = (float*)d_out;

  const int N = NNODE;
  const int E = in_sizes[1] / 2;

  char* base = (char*)d_ws;
  size_t off = 0;
  auto alloc = [&](size_t bytes) -> void* {
    void* p = base + off;
    off += (bytes + 255) & ~(size_t)255;
    return p;
  };
  u16*    hf16   = (u16*)alloc((size_t)N * NC * 2);     // 25.6 MB packed [node][c][h]
  float*  al_s   = (float*)alloc((size_t)N * NH * 4);
  float*  al_d   = (float*)alloc((size_t)N * NH * 4);
  float*  h1     = (float*)alloc((size_t)N * HID * 4);  // layer-1 output (relu'd)
  int*    deg    = (int*)alloc((size_t)N * 4);
  int*    offs   = (int*)alloc((size_t)(N + 1) * 4);
  int*    cursor = (int*)alloc((size_t)N * 4);
  int*    csr    = (int*)alloc((size_t)E * 4);
  int*    csrd   = (int*)alloc((size_t)E * 4);
  float4* w      = (float4*)alloc((size_t)E * 16);      // 12.8 MB per-edge weights
  int*    bsums  = (int*)alloc(256 * 4);
  int*    boffs  = (int*)alloc(256 * 4);

  const int nodeBlocks = (N + 3) / 4;           // 12500, wave per node
  const int edgeBlocks = (E + 255) / 256;       // 3125
  const int scanBlocks = (N + 255) / 256;       // 196
  dim3 gemmGrid(NC / BN, (N + BM - 1) / BM);    // (4, 782)

  // --- CSR build (shared by both layers) ---
  zero_i32<<<(N + 255) / 256, 256, 0, stream>>>(deg, N);
  count_deg<<<edgeBlocks, 256, 0, stream>>>(ei, deg, E);
  scan_phase1<<<scanBlocks, 256, 0, stream>>>(deg, bsums, N);
  scan_phase2<<<1, 256, 0, stream>>>(bsums, boffs, scanBlocks, offs + N);
  scan_phase3<<<scanBlocks, 256, 0, stream>>>(deg, boffs, offs, cursor, N);
  scatter_edges<<<edgeBlocks, 256, 0, stream>>>(ei, cursor, csr, csrd, E);

  // --- layer 1 ---
  gemm_alpha_kernel<<<gemmGrid, 256, 0, stream>>>(x, W1, as1, ad1, hf16, al_s, al_d, N, FIN);
  edge_weights<<<edgeBlocks, 256, 0, stream>>>(csr, csrd, al_s, al_d, w, E);
  agg_kernel<false><<<nodeBlocks, 256, 0, stream>>>(hf16, w, offs, csr, b1, h1, N);

  // --- layer 2 ---
  gemm_alpha_kernel<<<gemmGrid, 256, 0, stream>>>(h1, W2, as2, ad2, hf16, al_s, al_d, N, HID);
  edge_weights<<<edgeBlocks, 256, 0, stream>>>(csr, csrd, al_s, al_d, w, E);
  agg_kernel<true><<<nodeBlocks, 256, 0, stream>>>(hf16, w, offs, csr, b2, out, N);
}

// Round 5
// 385.376 us; speedup vs baseline: 1.7917x; 1.1717x over previous
//
#include <hip/hip_runtime.h>
#include <math.h>

// Problem constants (GATModel: N=50000, E=800000, F_IN=128, HID=OUT=64, H=4)
constexpr int NNODE = 50000;
constexpr int FIN   = 128;
constexpr int HID   = 64;
constexpr int NH    = 4;
constexpr int NC    = 256;   // NH * HID
constexpr float NEG = 0.2f;
constexpr int MPAD  = 50048; // NNODE padded to 64-row tiles (782*64)

typedef unsigned short u16;
typedef short bf16x8 __attribute__((ext_vector_type(8)));
typedef float f32x4 __attribute__((ext_vector_type(4)));

__device__ __forceinline__ u16 f2bf(float f) {  // round-to-nearest-even
  unsigned int u = __float_as_uint(f);
  return (u16)((u + 0x7FFF + ((u >> 16) & 1)) >> 16);
}
__device__ __forceinline__ float bf2f(u16 h) {
  return __uint_as_float(((unsigned int)h) << 16);
}
__device__ __forceinline__ float readlane_f(float v, int l) {
  return __int_as_float(__builtin_amdgcn_readlane(__float_as_int(v), l));
}

// ---------------- utility ----------------
__global__ __launch_bounds__(256) void zero_i32(int* __restrict__ p, int n) {
  int i = blockIdx.x * 256 + threadIdx.x;
  if (i < n) p[i] = 0;
}

// convert fp32 -> bf16, vectorized (n multiple of 4)
__global__ __launch_bounds__(256) void cvt_bf16(const float4* __restrict__ in, ushort4* __restrict__ out, int n4) {
  int i = blockIdx.x * 256 + threadIdx.x;
  if (i >= n4) return;
  float4 v = in[i];
  out[i] = make_ushort4(f2bf(v.x), f2bf(v.y), f2bf(v.z), f2bf(v.w));
}

// pack W[K][256] fp32 -> Bp bf16 in MFMA B-fragment order: Bp[(k>>3)*256 + n][k&7]
__global__ __launch_bounds__(256) void pack_W(const float* __restrict__ W, u16* __restrict__ Bp, int total) {
  int i = blockIdx.x * 256 + threadIdx.x;  // i = k*256 + n
  if (i >= total) return;
  int k = i >> 8, n = i & 255;
  Bp[((size_t)(k >> 3) * 256 + n) * 8 + (k & 7)] = f2bf(W[i]);
}

// ---------------- CSR build (by destination) ----------------
__global__ __launch_bounds__(256) void count_deg(const int* __restrict__ ei, int* __restrict__ deg, int E) {
  int i = blockIdx.x * 256 + threadIdx.x;
  if (i < E) atomicAdd(&deg[ei[E + i]], 1);
}

__global__ __launch_bounds__(256) void scan_phase1(const int* __restrict__ deg,
                                                   int* __restrict__ blockSums, int n) {
  __shared__ int sm[256];
  int tid = threadIdx.x;
  int i = blockIdx.x * 256 + tid;
  sm[tid] = (i < n) ? deg[i] : 0;
  __syncthreads();
#pragma unroll
  for (int o = 128; o > 0; o >>= 1) {
    if (tid < o) sm[tid] += sm[tid + o];
    __syncthreads();
  }
  if (tid == 0) blockSums[blockIdx.x] = sm[0];
}

__global__ __launch_bounds__(256) void scan_phase2(const int* __restrict__ blockSums,
                                                   int* __restrict__ blockOffs, int nb,
                                                   int* __restrict__ total_out) {
  __shared__ int sm[256];
  int tid = threadIdx.x;
  int v = (tid < nb) ? blockSums[tid] : 0;
  sm[tid] = v;
  __syncthreads();
#pragma unroll
  for (int o = 1; o < 256; o <<= 1) {
    int t = (tid >= o) ? sm[tid - o] : 0;
    __syncthreads();
    sm[tid] += t;
    __syncthreads();
  }
  if (tid < nb) blockOffs[tid] = sm[tid] - v;  // exclusive
  if (tid == 255) *total_out = sm[255];        // offs[N] = E
}

__global__ __launch_bounds__(256) void scan_phase3(const int* __restrict__ deg,
                                                   const int* __restrict__ blockOffs,
                                                   int* __restrict__ offs, int* __restrict__ cursor, int n) {
  __shared__ int sm[256];
  int tid = threadIdx.x;
  int i = blockIdx.x * 256 + tid;
  int v = (i < n) ? deg[i] : 0;
  sm[tid] = v;
  __syncthreads();
#pragma unroll
  for (int o = 1; o < 256; o <<= 1) {
    int t = (tid >= o) ? sm[tid - o] : 0;
    __syncthreads();
    sm[tid] += t;
    __syncthreads();
  }
  int ex = sm[tid] - v + blockOffs[blockIdx.x];
  if (i < n) { offs[i] = ex; cursor[i] = ex; }
}

__global__ __launch_bounds__(256) void scatter_edges(const int* __restrict__ ei, int* __restrict__ cursor,
                                                     int* __restrict__ csr_src, int* __restrict__ csr_dst, int E) {
  int i = blockIdx.x * 256 + threadIdx.x;
  if (i < E) {
    int dst = ei[E + i];
    int pos = atomicAdd(&cursor[dst], 1);
    csr_src[pos] = ei[i];
    csr_dst[pos] = dst;
  }
}

// ---------------- per-edge attention weights ----------------
__global__ __launch_bounds__(256) void edge_weights(const int* __restrict__ csr_src,
                                                    const int* __restrict__ csr_dst,
                                                    const float* __restrict__ al_s,
                                                    const float* __restrict__ al_d,
                                                    float4* __restrict__ w, int E) {
  int i = blockIdx.x * 256 + threadIdx.x;
  if (i >= E) return;
  float4 a = ((const float4*)al_s)[csr_src[i]];
  float4 b = ((const float4*)al_d)[csr_dst[i]];
  float e0 = a.x + b.x; e0 = e0 >= 0.f ? e0 : NEG * e0;
  float e1 = a.y + b.y; e1 = e1 >= 0.f ? e1 : NEG * e1;
  float e2 = a.z + b.z; e2 = e2 >= 0.f ? e2 : NEG * e2;
  float e3 = a.w + b.w; e3 = e3 >= 0.f ? e3 : NEG * e3;
  w[i] = make_float4(__expf(e0), __expf(e1), __expf(e2), __expf(e3));
}

// ---------------- MFMA bf16 GEMM + alpha + packed bf16 store ----------------
// C[M,256] = A[M,K]bf16 @ B[K,256]bf16 (B pre-packed in fragment order).
// Block = 256 thr = 4 waves; wave computes 16 rows x 256 cols via 16x16x32 MFMA.
// A-frag: lane holds A[m = lane&15][k = (lane>>4)*8 + j]  (row-major bf16: 16B load)
// B-frag: lane holds B[k = (lane>>4)*8 + j][n = lane&15]  (packed Bp)
// D: col = lane&15, row = (lane>>4)*4 + reg   [m89/m91-verified layouts]
template <int KS>  // K = 32*KS
__global__ __launch_bounds__(256) void gemm_mfma(
    const u16* __restrict__ Abf, const u16* __restrict__ Bp,
    const float* __restrict__ a_s, const float* __restrict__ a_d,
    u16* __restrict__ hf16, float* __restrict__ al_s, float* __restrict__ al_d, int M) {
  const int K = 32 * KS;
  int lane = threadIdx.x & 63;
  int wv = threadIdx.x >> 6;
  int q = lane >> 4, r = lane & 15;
  int m0 = blockIdx.x * 64 + wv * 16;

  bf16x8 af[KS];
  const u16* arow = Abf + (size_t)(m0 + r) * K + q * 8;
#pragma unroll
  for (int ks = 0; ks < KS; ++ks) af[ks] = *(const bf16x8*)(arow + ks * 32);

  int node_base = m0 + q * 4;
#pragma unroll
  for (int h = 0; h < NH; ++h) {
    f32x4 acc[4];
#pragma unroll
    for (int c4 = 0; c4 < 4; ++c4) {
      acc[c4] = (f32x4){0.f, 0.f, 0.f, 0.f};
      const u16* bp = Bp + ((size_t)q * 256 + (h * 4 + c4) * 16 + r) * 8;
#pragma unroll
      for (int ks = 0; ks < KS; ++ks) {
        bf16x8 bf = *(const bf16x8*)(bp + (size_t)ks * 4 * 256 * 8);
        acc[c4] = __builtin_amdgcn_mfma_f32_16x16x32_bf16(af[ks], bf, acc[c4], 0, 0, 0);
      }
    }
    // epilogue for this head: alpha partials + packed bf16 stores
    float ps[4] = {0.f, 0.f, 0.f, 0.f}, pd[4] = {0.f, 0.f, 0.f, 0.f};
#pragma unroll
    for (int c4 = 0; c4 < 4; ++c4) {
      float sa = a_s[h * HID + c4 * 16 + r];
      float da = a_d[h * HID + c4 * 16 + r];
#pragma unroll
      for (int reg = 0; reg < 4; ++reg) {
        float v = acc[c4][reg];
        ps[reg] += v * sa;
        pd[reg] += v * da;
        int node = node_base + reg;
        if (node < M) hf16[(size_t)node * NC + (c4 * 16 + r) * NH + h] = f2bf(v);
      }
    }
#pragma unroll
    for (int reg = 0; reg < 4; ++reg) {
#pragma unroll
      for (int o = 1; o < 16; o <<= 1) {
        ps[reg] += __shfl_xor(ps[reg], o);
        pd[reg] += __shfl_xor(pd[reg], o);
      }
      int node = node_base + reg;
      if (r == 0 && node < M) {
        al_s[node * NH + h] = ps[reg];
        al_d[node * NH + h] = pd[reg];
      }
    }
  }
}

// ---------------- aggregation: one wave per destination node ----------------
// Chunk-of-8 structure: batch-load 8 indices + 32 weights coalesced, readlane
// into SGPRs (scalar gather addressing), 8 gathers in flight before first use.
template <bool FINAL>
__global__ __launch_bounds__(256) void agg_kernel(const u16* __restrict__ hf16,
                                                  const float* __restrict__ wf,
                                                  const int* __restrict__ offs, const int* __restrict__ csr_src,
                                                  const float* __restrict__ bias, void* __restrict__ out_v, int n) {
  int lane = threadIdx.x & 63;
  int node = blockIdx.x * 4 + (threadIdx.x >> 6);
  if (node >= n) return;
  float c0 = 0.f, c1 = 0.f, c2 = 0.f, c3 = 0.f;
  float d0 = 0.f, d1 = 0.f, d2 = 0.f, d3 = 0.f;
  int s = offs[node], e = offs[node + 1];
  int i = s;
  int nfull = (e - s) >> 3;
  for (int ch = 0; ch < nfull; ++ch, i += 8) {
    int vidx = csr_src[i + (lane & 7)];
    float vw = wf[i * 4 + (lane & 31)];
    ushort4 hv[8];
#pragma unroll
    for (int j = 0; j < 8; ++j) {
      int sa = __builtin_amdgcn_readlane(vidx, j);
      hv[j] = ((const ushort4*)(hf16 + (size_t)sa * NC))[lane];
    }
#pragma unroll
    for (int j = 0; j < 8; ++j) {
      float wx = readlane_f(vw, 4 * j + 0);
      float wy = readlane_f(vw, 4 * j + 1);
      float wz = readlane_f(vw, 4 * j + 2);
      float ww = readlane_f(vw, 4 * j + 3);
      c0 += wx * bf2f(hv[j].x); d0 += wx;
      c1 += wy * bf2f(hv[j].y); d1 += wy;
      c2 += wz * bf2f(hv[j].z); d2 += wz;
      c3 += ww * bf2f(hv[j].w); d3 += ww;
    }
  }
  for (; i < e; ++i) {
    int sa = csr_src[i];
    float4 wa = ((const float4*)wf)[i];
    ushort4 ha = ((const ushort4*)(hf16 + (size_t)sa * NC))[lane];
    c0 += wa.x * bf2f(ha.x); d0 += wa.x;
    c1 += wa.y * bf2f(ha.y); d1 += wa.y;
    c2 += wa.z * bf2f(ha.z); d2 += wa.z;
    c3 += wa.w * bf2f(ha.w); d3 += wa.w;
  }
  float val = 0.25f * (c0 / (d0 + 1e-16f) + c1 / (d1 + 1e-16f) +
                       c2 / (d2 + 1e-16f) + c3 / (d3 + 1e-16f)) + bias[lane];
  if (!FINAL) {
    // layer-1 output: relu + bf16 (feeds layer-2 MFMA GEMM directly)
    ((u16*)out_v)[(size_t)node * HID + lane] = f2bf(fmaxf(val, 0.f));
  } else {
    float mx = val;
#pragma unroll
    for (int o = 32; o >= 1; o >>= 1) mx = fmaxf(mx, __shfl_xor(mx, o));
    float ex = __expf(val - mx);
    float sm = ex;
#pragma unroll
    for (int o = 32; o >= 1; o >>= 1) sm += __shfl_xor(sm, o);
    ((float*)out_v)[(size_t)node * HID + lane] = (val - mx) - logf(sm);
  }
}

// ---------------- launch ----------------
extern "C" void kernel_launch(void* const* d_in, const int* in_sizes, int n_in,
                              void* d_out, int out_size, void* d_ws, size_t ws_size,
                              hipStream_t stream) {
  const float* x   = (const float*)d_in[0];
  const int*   ei  = (const int*)d_in[1];   // int32 (JAX x64 disabled canonicalizes int64)
  const float* W1  = (const float*)d_in[2];
  const float* as1 = (const float*)d_in[3];
  const float* ad1 = (const float*)d_in[4];
  const float* b1  = (const float*)d_in[5];
  const float* W2  = (const float*)d_in[6];
  const float* as2 = (const float*)d_in[7];
  const float* ad2 = (const float*)d_in[8];
  const float* b2  = (const float*)d_in[9];
  float* out = (float*)d_out;

  const int N = NNODE;
  const int E = in_sizes[1] / 2;

  char* base = (char*)d_ws;
  size_t off = 0;
  auto alloc = [&](size_t bytes) -> void* {
    void* p = base + off;
    off += (bytes + 255) & ~(size_t)255;
    return p;
  };
  u16*    hf16   = (u16*)alloc((size_t)N * NC * 2);       // 25.6 MB packed [node][c][h]
  u16*    xbf    = (u16*)alloc((size_t)MPAD * FIN * 2);   // 12.8 MB bf16 x (padded rows)
  u16*    h1bf   = (u16*)alloc((size_t)MPAD * HID * 2);   // 6.4 MB bf16 layer-1 out (padded)
  u16*    Bp1    = (u16*)alloc((size_t)FIN * NC * 2);     // packed W1
  u16*    Bp2    = (u16*)alloc((size_t)HID * NC * 2);     // packed W2
  float*  al_s   = (float*)alloc((size_t)N * NH * 4);
  float*  al_d   = (float*)alloc((size_t)N * NH * 4);
  int*    deg    = (int*)alloc((size_t)N * 4);
  int*    offs   = (int*)alloc((size_t)(N + 1) * 4);
  int*    cursor = (int*)alloc((size_t)N * 4);
  int*    csr    = (int*)alloc((size_t)E * 4);
  int*    csrd   = (int*)alloc((size_t)E * 4);
  float4* w      = (float4*)alloc((size_t)E * 16);        // 12.8 MB per-edge weights
  int*    bsums  = (int*)alloc(256 * 4);
  int*    boffs  = (int*)alloc(256 * 4);

  const int nodeBlocks = (N + 3) / 4;           // 12500, wave per node
  const int edgeBlocks = (E + 255) / 256;       // 3125
  const int scanBlocks = (N + 255) / 256;       // 196
  const int gemmBlocks = MPAD / 64;             // 782

  // --- CSR build (shared by both layers) ---
  zero_i32<<<(N + 255) / 256, 256, 0, stream>>>(deg, N);
  count_deg<<<edgeBlocks, 256, 0, stream>>>(ei, deg, E);
  scan_phase1<<<scanBlocks, 256, 0, stream>>>(deg, bsums, N);
  scan_phase2<<<1, 256, 0, stream>>>(bsums, boffs, scanBlocks, offs + N);
  scan_phase3<<<scanBlocks, 256, 0, stream>>>(deg, boffs, offs, cursor, N);
  scatter_edges<<<edgeBlocks, 256, 0, stream>>>(ei, cursor, csr, csrd, E);

  // --- bf16 conversions / weight packing ---
  cvt_bf16<<<(N * FIN / 4 + 255) / 256, 256, 0, stream>>>((const float4*)x, (ushort4*)xbf, N * FIN / 4);
  pack_W<<<(FIN * NC + 255) / 256, 256, 0, stream>>>(W1, Bp1, FIN * NC);
  pack_W<<<(HID * NC + 255) / 256, 256, 0, stream>>>(W2, Bp2, HID * NC);

  // --- layer 1 ---
  gemm_mfma<4><<<gemmBlocks, 256, 0, stream>>>(xbf, Bp1, as1, ad1, hf16, al_s, al_d, N);
  edge_weights<<<edgeBlocks, 256, 0, stream>>>(csr, csrd, al_s, al_d, w, E);
  agg_kernel<false><<<nodeBlocks, 256, 0, stream>>>(hf16, (const float*)w, offs, csr, b1, h1bf, N);

  // --- layer 2 ---
  gemm_mfma<2><<<gemmBlocks, 256, 0, stream>>>(h1bf, Bp2, as2, ad2, hf16, al_s, al_d, N);
  edge_weights<<<edgeBlocks, 256, 0, stream>>>(csr, csrd, al_s, al_d, w, E);
  agg_kernel<true><<<nodeBlocks, 256, 0, stream>>>(hf16, (const float*)w, offs, csr, b2, out, N);
}

// Round 6
// 374.852 us; speedup vs baseline: 1.8421x; 1.0281x over previous
//
#include <hip/hip_runtime.h>
#include <math.h>

// Problem constants (GATModel: N=50000, E=800000, F_IN=128, HID=OUT=64, H=4)
constexpr int NNODE = 50000;
constexpr int FIN   = 128;
constexpr int HID   = 64;
constexpr int NH    = 4;
constexpr int NC    = 256;   // NH * HID
constexpr float NEG = 0.2f;
constexpr int MPAD  = 50048; // NNODE padded to 64-row tiles (782*64)

typedef unsigned short u16;
typedef short bf16x8 __attribute__((ext_vector_type(8)));
typedef float f32x4 __attribute__((ext_vector_type(4)));

__device__ __forceinline__ u16 f2bf(float f) {  // round-to-nearest-even
  unsigned int u = __float_as_uint(f);
  return (u16)((u + 0x7FFF + ((u >> 16) & 1)) >> 16);
}
__device__ __forceinline__ float bf2f(u16 h) {
  return __uint_as_float(((unsigned int)h) << 16);
}
__device__ __forceinline__ float readlane_f(float v, int l) {
  return __int_as_float(__builtin_amdgcn_readlane(__float_as_int(v), l));
}

// ---------------- utility ----------------
__global__ __launch_bounds__(256) void zero_i32(int* __restrict__ p, int n) {
  int i = blockIdx.x * 256 + threadIdx.x;
  if (i < n) p[i] = 0;
}

// pack W[K][256] fp32 -> Bp bf16 in MFMA B-fragment order: Bp[(k>>3)*256 + n][k&7]
__global__ __launch_bounds__(256) void pack_W(const float* __restrict__ W, u16* __restrict__ Bp, int total) {
  int i = blockIdx.x * 256 + threadIdx.x;  // i = k*256 + n
  if (i >= total) return;
  int k = i >> 8, n = i & 255;
  Bp[((size_t)(k >> 3) * 256 + n) * 8 + (k & 7)] = f2bf(W[i]);
}

// ---------------- CSR build (by destination) ----------------
__global__ __launch_bounds__(256) void count_deg(const int* __restrict__ ei, int* __restrict__ deg, int E) {
  int i = blockIdx.x * 256 + threadIdx.x;
  if (i < E) atomicAdd(&deg[ei[E + i]], 1);
}

__global__ __launch_bounds__(256) void scan_phase1(const int* __restrict__ deg,
                                                   int* __restrict__ blockSums, int n) {
  __shared__ int sm[256];
  int tid = threadIdx.x;
  int i = blockIdx.x * 256 + tid;
  sm[tid] = (i < n) ? deg[i] : 0;
  __syncthreads();
#pragma unroll
  for (int o = 128; o > 0; o >>= 1) {
    if (tid < o) sm[tid] += sm[tid + o];
    __syncthreads();
  }
  if (tid == 0) blockSums[blockIdx.x] = sm[0];
}

__global__ __launch_bounds__(256) void scan_phase2(const int* __restrict__ blockSums,
                                                   int* __restrict__ blockOffs, int nb,
                                                   int* __restrict__ total_out) {
  __shared__ int sm[256];
  int tid = threadIdx.x;
  int v = (tid < nb) ? blockSums[tid] : 0;
  sm[tid] = v;
  __syncthreads();
#pragma unroll
  for (int o = 1; o < 256; o <<= 1) {
    int t = (tid >= o) ? sm[tid - o] : 0;
    __syncthreads();
    sm[tid] += t;
    __syncthreads();
  }
  if (tid < nb) blockOffs[tid] = sm[tid] - v;  // exclusive
  if (tid == 255) *total_out = sm[255];        // offs[N] = E
}

__global__ __launch_bounds__(256) void scan_phase3(const int* __restrict__ deg,
                                                   const int* __restrict__ blockOffs,
                                                   int* __restrict__ offs, int* __restrict__ cursor, int n) {
  __shared__ int sm[256];
  int tid = threadIdx.x;
  int i = blockIdx.x * 256 + tid;
  int v = (i < n) ? deg[i] : 0;
  sm[tid] = v;
  __syncthreads();
#pragma unroll
  for (int o = 1; o < 256; o <<= 1) {
    int t = (tid >= o) ? sm[tid - o] : 0;
    __syncthreads();
    sm[tid] += t;
    __syncthreads();
  }
  int ex = sm[tid] - v + blockOffs[blockIdx.x];
  if (i < n) { offs[i] = ex; cursor[i] = ex; }
}

__global__ __launch_bounds__(256) void scatter_edges(const int* __restrict__ ei, int* __restrict__ cursor,
                                                     int* __restrict__ csr_src, int E) {
  int i = blockIdx.x * 256 + threadIdx.x;
  if (i < E) {
    int dst = ei[E + i];
    int pos = atomicAdd(&cursor[dst], 1);
    csr_src[pos] = ei[i];
  }
}

// ---------------- MFMA bf16 GEMM + alpha + packed bf16 store ----------------
// C[M,256] = A[M,K] @ B[K,256]bf16 (B pre-packed in fragment order).
// A read as fp32 (AF32=true, converted in-register) or bf16.
// A-frag: lane holds A[m = lane&15][k = (lane>>4)*8 + j]
// B-frag: lane holds B[k = (lane>>4)*8 + j][n = lane&15]  (packed Bp)
// D: col = lane&15, row = (lane>>4)*4 + reg   [m89/m91-verified layouts]
template <int KS, bool AF32>  // K = 32*KS
__global__ __launch_bounds__(256) void gemm_mfma(
    const void* __restrict__ Aptr, const u16* __restrict__ Bp,
    const float* __restrict__ a_s, const float* __restrict__ a_d,
    u16* __restrict__ hf16, float* __restrict__ al_s, float* __restrict__ al_d, int M) {
  const int K = 32 * KS;
  int lane = threadIdx.x & 63;
  int wv = threadIdx.x >> 6;
  int q = lane >> 4, r = lane & 15;
  int m0 = blockIdx.x * 64 + wv * 16;

  bf16x8 af[KS];
  if (AF32) {
    int ar = m0 + r; if (ar >= M) ar = M - 1;   // x has exactly M rows; clamp (stores guarded)
    const float* arow = (const float*)Aptr + (size_t)ar * K + q * 8;
#pragma unroll
    for (int ks = 0; ks < KS; ++ks) {
      float4 v0 = *(const float4*)(arow + ks * 32);
      float4 v1 = *(const float4*)(arow + ks * 32 + 4);
      bf16x8 t;
      t[0] = (short)f2bf(v0.x); t[1] = (short)f2bf(v0.y);
      t[2] = (short)f2bf(v0.z); t[3] = (short)f2bf(v0.w);
      t[4] = (short)f2bf(v1.x); t[5] = (short)f2bf(v1.y);
      t[6] = (short)f2bf(v1.z); t[7] = (short)f2bf(v1.w);
      af[ks] = t;
    }
  } else {
    const u16* arow = (const u16*)Aptr + (size_t)(m0 + r) * K + q * 8;  // padded buffer
#pragma unroll
    for (int ks = 0; ks < KS; ++ks) af[ks] = *(const bf16x8*)(arow + ks * 32);
  }

  int node_base = m0 + q * 4;
#pragma unroll
  for (int h = 0; h < NH; ++h) {
    f32x4 acc[4];
#pragma unroll
    for (int c4 = 0; c4 < 4; ++c4) {
      acc[c4] = (f32x4){0.f, 0.f, 0.f, 0.f};
      const u16* bp = Bp + ((size_t)q * 256 + (h * 4 + c4) * 16 + r) * 8;
#pragma unroll
      for (int ks = 0; ks < KS; ++ks) {
        bf16x8 bf = *(const bf16x8*)(bp + (size_t)ks * 4 * 256 * 8);
        acc[c4] = __builtin_amdgcn_mfma_f32_16x16x32_bf16(af[ks], bf, acc[c4], 0, 0, 0);
      }
    }
    // epilogue for this head: alpha partials + packed bf16 stores
    float ps[4] = {0.f, 0.f, 0.f, 0.f}, pd[4] = {0.f, 0.f, 0.f, 0.f};
#pragma unroll
    for (int c4 = 0; c4 < 4; ++c4) {
      float sa = a_s[h * HID + c4 * 16 + r];
      float da = a_d[h * HID + c4 * 16 + r];
#pragma unroll
      for (int reg = 0; reg < 4; ++reg) {
        float v = acc[c4][reg];
        ps[reg] += v * sa;
        pd[reg] += v * da;
        int node = node_base + reg;
        if (node < M) hf16[(size_t)node * NC + (c4 * 16 + r) * NH + h] = f2bf(v);
      }
    }
#pragma unroll
    for (int reg = 0; reg < 4; ++reg) {
#pragma unroll
      for (int o = 1; o < 16; o <<= 1) {
        ps[reg] += __shfl_xor(ps[reg], o);
        pd[reg] += __shfl_xor(pd[reg], o);
      }
      int node = node_base + reg;
      if (r == 0 && node < M) {
        al_s[node * NH + h] = ps[reg];
        al_d[node * NH + h] = pd[reg];
      }
    }
  }
}

// ---------------- aggregation: one wave per destination node ----------------
// Chunk-of-8: batch-load 8 src indices, gather al_s per edge, lanes 0..31 each
// compute ONE exp for one (edge,head), broadcast via readlane. No max-shift:
// logits bounded ~|e|<20 => exp(e)/sum identical to reference's shifted softmax.
template <bool FINAL>
__global__ __launch_bounds__(256) void agg_kernel(const u16* __restrict__ hf16,
                                                  const float4* __restrict__ al_s4,
                                                  const float4* __restrict__ al_d4,
                                                  const int* __restrict__ offs, const int* __restrict__ csr_src,
                                                  const float* __restrict__ bias, void* __restrict__ out_v, int n) {
  int lane = threadIdx.x & 63;
  int node = blockIdx.x * 4 + (threadIdx.x >> 6);
  if (node >= n) return;
  float4 ad = al_d4[node];
  int hsel = (lane >> 3) & 3;  // head handled by this lane in the weight phase
  float adv = hsel == 0 ? ad.x : (hsel == 1 ? ad.y : (hsel == 2 ? ad.z : ad.w));
  float c0 = 0.f, c1 = 0.f, c2 = 0.f, c3 = 0.f;
  float d0 = 0.f, d1 = 0.f, d2 = 0.f, d3 = 0.f;
  int s = offs[node], e = offs[node + 1];
  int i = s;
  int nfull = (e - s) >> 3;
  for (int ch = 0; ch < nfull; ++ch, i += 8) {
    int vidx = csr_src[i + (lane & 7)];
    float4 as = al_s4[vidx];                       // gather, 8 distinct lines
    ushort4 hv[8];
#pragma unroll
    for (int j = 0; j < 8; ++j) {
      int sa = __builtin_amdgcn_readlane(vidx, j);
      hv[j] = ((const ushort4*)(hf16 + (size_t)sa * NC))[lane];  // 8 gathers in flight
    }
    float asv = hsel == 0 ? as.x : (hsel == 1 ? as.y : (hsel == 2 ? as.z : as.w));
    float ev = asv + adv;
    ev = ev >= 0.f ? ev : NEG * ev;
    float wv = __expf(ev);  // lane 8*h + j holds w[edge j][head h] (lanes 0..31)
#pragma unroll
    for (int j = 0; j < 8; ++j) {
      float wx = readlane_f(wv, j);
      float wy = readlane_f(wv, 8 + j);
      float wz = readlane_f(wv, 16 + j);
      float ww = readlane_f(wv, 24 + j);
      c0 += wx * bf2f(hv[j].x); d0 += wx;
      c1 += wy * bf2f(hv[j].y); d1 += wy;
      c2 += wz * bf2f(hv[j].z); d2 += wz;
      c3 += ww * bf2f(hv[j].w); d3 += ww;
    }
  }
  for (; i < e; ++i) {  // tail (<8 edges): redundant per-lane weight math
    int sa = csr_src[i];
    float4 as = al_s4[sa];
    ushort4 ha = ((const ushort4*)(hf16 + (size_t)sa * NC))[lane];
    float e0 = as.x + ad.x; e0 = e0 >= 0.f ? e0 : NEG * e0; float w0 = __expf(e0);
    float e1 = as.y + ad.y; e1 = e1 >= 0.f ? e1 : NEG * e1; float w1 = __expf(e1);
    float e2 = as.z + ad.z; e2 = e2 >= 0.f ? e2 : NEG * e2; float w2 = __expf(e2);
    float e3 = as.w + ad.w; e3 = e3 >= 0.f ? e3 : NEG * e3; float w3 = __expf(e3);
    c0 += w0 * bf2f(ha.x); d0 += w0;
    c1 += w1 * bf2f(ha.y); d1 += w1;
    c2 += w2 * bf2f(ha.z); d2 += w2;
    c3 += w3 * bf2f(ha.w); d3 += w3;
  }
  float val = 0.25f * (c0 / (d0 + 1e-16f) + c1 / (d1 + 1e-16f) +
                       c2 / (d2 + 1e-16f) + c3 / (d3 + 1e-16f)) + bias[lane];
  if (!FINAL) {
    // layer-1 output: relu + bf16 (feeds layer-2 MFMA GEMM directly)
    ((u16*)out_v)[(size_t)node * HID + lane] = f2bf(fmaxf(val, 0.f));
  } else {
    float mx = val;
#pragma unroll
    for (int o = 32; o >= 1; o >>= 1) mx = fmaxf(mx, __shfl_xor(mx, o));
    float ex = __expf(val - mx);
    float sm = ex;
#pragma unroll
    for (int o = 32; o >= 1; o >>= 1) sm += __shfl_xor(sm, o);
    ((float*)out_v)[(size_t)node * HID + lane] = (val - mx) - logf(sm);
  }
}

// ---------------- launch ----------------
extern "C" void kernel_launch(void* const* d_in, const int* in_sizes, int n_in,
                              void* d_out, int out_size, void* d_ws, size_t ws_size,
                              hipStream_t stream) {
  const float* x   = (const float*)d_in[0];
  const int*   ei  = (const int*)d_in[1];   // int32 (JAX x64 disabled canonicalizes int64)
  const float* W1  = (const float*)d_in[2];
  const float* as1 = (const float*)d_in[3];
  const float* ad1 = (const float*)d_in[4];
  const float* b1  = (const float*)d_in[5];
  const float* W2  = (const float*)d_in[6];
  const float* as2 = (const float*)d_in[7];
  const float* ad2 = (const float*)d_in[8];
  const float* b2  = (const float*)d_in[9];
  float* out = (float*)d_out;

  const int N = NNODE;
  const int E = in_sizes[1] / 2;

  char* base = (char*)d_ws;
  size_t off = 0;
  auto alloc = [&](size_t bytes) -> void* {
    void* p = base + off;
    off += (bytes + 255) & ~(size_t)255;
    return p;
  };
  u16*    hf16   = (u16*)alloc((size_t)N * NC * 2);       // 25.6 MB packed [node][c][h]
  u16*    h1bf   = (u16*)alloc((size_t)MPAD * HID * 2);   // 6.4 MB bf16 layer-1 out (padded)
  u16*    Bp1    = (u16*)alloc((size_t)FIN * NC * 2);     // packed W1
  u16*    Bp2    = (u16*)alloc((size_t)HID * NC * 2);     // packed W2
  float*  al_s   = (float*)alloc((size_t)N * NH * 4);
  float*  al_d   = (float*)alloc((size_t)N * NH * 4);
  int*    deg    = (int*)alloc((size_t)N * 4);
  int*    offs   = (int*)alloc((size_t)(N + 1) * 4);
  int*    cursor = (int*)alloc((size_t)N * 4);
  int*    csr    = (int*)alloc((size_t)E * 4);
  int*    bsums  = (int*)alloc(256 * 4);
  int*    boffs  = (int*)alloc(256 * 4);

  const int nodeBlocks = (N + 3) / 4;           // 12500, wave per node
  const int edgeBlocks = (E + 255) / 256;       // 3125
  const int scanBlocks = (N + 255) / 256;       // 196
  const int gemmBlocks = MPAD / 64;             // 782

  // --- CSR build (shared by both layers) ---
  zero_i32<<<(N + 255) / 256, 256, 0, stream>>>(deg, N);
  count_deg<<<edgeBlocks, 256, 0, stream>>>(ei, deg, E);
  scan_phase1<<<scanBlocks, 256, 0, stream>>>(deg, bsums, N);
  scan_phase2<<<1, 256, 0, stream>>>(bsums, boffs, scanBlocks, offs + N);
  scan_phase3<<<scanBlocks, 256, 0, stream>>>(deg, boffs, offs, cursor, N);
  scatter_edges<<<edgeBlocks, 256, 0, stream>>>(ei, cursor, csr, E);

  // --- weight packing ---
  pack_W<<<(FIN * NC + 255) / 256, 256, 0, stream>>>(W1, Bp1, FIN * NC);
  pack_W<<<(HID * NC + 255) / 256, 256, 0, stream>>>(W2, Bp2, HID * NC);

  // --- layer 1 (A = x fp32, converted in-register) ---
  gemm_mfma<4, true><<<gemmBlocks, 256, 0, stream>>>(x, Bp1, as1, ad1, hf16, al_s, al_d, N);
  agg_kernel<false><<<nodeBlocks, 256, 0, stream>>>(hf16, (const float4*)al_s, (const float4*)al_d,
                                                    offs, csr, b1, h1bf, N);

  // --- layer 2 (A = h1bf bf16) ---
  gemm_mfma<2, false><<<gemmBlocks, 256, 0, stream>>>(h1bf, Bp2, as2, ad2, hf16, al_s, al_d, N);
  agg_kernel<true><<<nodeBlocks, 256, 0, stream>>>(hf16, (const float4*)al_s, (const float4*)al_d,
                                                   offs, csr, b2, out, N);
}

// Round 7
// 365.124 us; speedup vs baseline: 1.8911x; 1.0266x over previous
//
#include <hip/hip_runtime.h>
#include <math.h>

// Problem constants (GATModel: N=50000, E=800000, F_IN=128, HID=OUT=64, H=4)
constexpr int NNODE = 50000;
constexpr int FIN   = 128;
constexpr int HID   = 64;
constexpr int NH    = 4;
constexpr int NC    = 256;   // NH * HID
constexpr float NEG = 0.2f;
constexpr int MPAD  = 50048; // NNODE padded to 64-row tiles (782*64)

typedef unsigned short u16;
typedef short bf16x8 __attribute__((ext_vector_type(8)));
typedef float f32x4 __attribute__((ext_vector_type(4)));

__device__ __forceinline__ u16 f2bf(float f) {  // round-to-nearest-even
  unsigned int u = __float_as_uint(f);
  return (u16)((u + 0x7FFF + ((u >> 16) & 1)) >> 16);
}
__device__ __forceinline__ float bf2f(u16 h) {
  return __uint_as_float(((unsigned int)h) << 16);
}
__device__ __forceinline__ float readlane_f(float v, int l) {
  return __int_as_float(__builtin_amdgcn_readlane(__float_as_int(v), l));
}

// pack W[K][256] fp32 -> Bp bf16 in MFMA B-fragment order: Bp[(k>>3)*256 + n][k&7]
__global__ __launch_bounds__(256) void pack_W(const float* __restrict__ W, u16* __restrict__ Bp, int total) {
  int i = blockIdx.x * 256 + threadIdx.x;  // i = k*256 + n
  if (i >= total) return;
  int k = i >> 8, n = i & 255;
  Bp[((size_t)(k >> 3) * 256 + n) * 8 + (k & 7)] = f2bf(W[i]);
}

// ---------------- CSR build (by destination) ----------------
__global__ __launch_bounds__(256) void count_deg(const int* __restrict__ ei, int* __restrict__ deg, int E) {
  int i = blockIdx.x * 256 + threadIdx.x;
  if (i < E) atomicAdd(&deg[ei[E + i]], 1);
}

__global__ __launch_bounds__(256) void scan_phase1(const int* __restrict__ deg,
                                                   int* __restrict__ blockSums, int n) {
  __shared__ int sm[256];
  int tid = threadIdx.x;
  int i = blockIdx.x * 256 + tid;
  sm[tid] = (i < n) ? deg[i] : 0;
  __syncthreads();
#pragma unroll
  for (int o = 128; o > 0; o >>= 1) {
    if (tid < o) sm[tid] += sm[tid + o];
    __syncthreads();
  }
  if (tid == 0) blockSums[blockIdx.x] = sm[0];
}

__global__ __launch_bounds__(256) void scan_phase2(const int* __restrict__ blockSums,
                                                   int* __restrict__ blockOffs, int nb,
                                                   int* __restrict__ total_out) {
  __shared__ int sm[256];
  int tid = threadIdx.x;
  int v = (tid < nb) ? blockSums[tid] : 0;
  sm[tid] = v;
  __syncthreads();
#pragma unroll
  for (int o = 1; o < 256; o <<= 1) {
    int t = (tid >= o) ? sm[tid - o] : 0;
    __syncthreads();
    sm[tid] += t;
    __syncthreads();
  }
  if (tid < nb) blockOffs[tid] = sm[tid] - v;  // exclusive
  if (tid == 255) *total_out = sm[255];        // offs[N] = E
}

__global__ __launch_bounds__(256) void scan_phase3(const int* __restrict__ deg,
                                                   const int* __restrict__ blockOffs,
                                                   int* __restrict__ offs, int* __restrict__ cursor, int n) {
  __shared__ int sm[256];
  int tid = threadIdx.x;
  int i = blockIdx.x * 256 + tid;
  int v = (i < n) ? deg[i] : 0;
  sm[tid] = v;
  __syncthreads();
#pragma unroll
  for (int o = 1; o < 256; o <<= 1) {
    int t = (tid >= o) ? sm[tid - o] : 0;
    __syncthreads();
    sm[tid] += t;
    __syncthreads();
  }
  int ex = sm[tid] - v + blockOffs[blockIdx.x];
  if (i < n) { offs[i] = ex; cursor[i] = ex; }
}

__global__ __launch_bounds__(256) void scatter_edges(const int* __restrict__ ei, int* __restrict__ cursor,
                                                     int* __restrict__ csr_src, int E) {
  int i = blockIdx.x * 256 + threadIdx.x;
  if (i < E) {
    int dst = ei[E + i];
    int pos = atomicAdd(&cursor[dst], 1);
    csr_src[pos] = ei[i];
  }
}

// ---------------- MFMA bf16 GEMM + alpha + packed bf16 store ----------------
// C[M,256] = A[M,K] @ B[K,256]bf16 (B pre-packed in fragment order).
// A-frag: lane holds A[m = lane&15][k = (lane>>4)*8 + j]
// B-frag: lane holds B[k = (lane>>4)*8 + j][n = lane&15]  (packed Bp)
// D: col = lane&15, row = (lane>>4)*4 + reg   [m89/m91-verified layouts]
template <int KS, bool AF32>  // K = 32*KS
__global__ __launch_bounds__(256) void gemm_mfma(
    const void* __restrict__ Aptr, const u16* __restrict__ Bp,
    const float* __restrict__ a_s, const float* __restrict__ a_d,
    u16* __restrict__ hf16, float* __restrict__ al_s, float* __restrict__ al_d, int M) {
  const int K = 32 * KS;
  int lane = threadIdx.x & 63;
  int wv = threadIdx.x >> 6;
  int q = lane >> 4, r = lane & 15;
  int m0 = blockIdx.x * 64 + wv * 16;

  bf16x8 af[KS];
  if (AF32) {
    int ar = m0 + r; if (ar >= M) ar = M - 1;   // x has exactly M rows; clamp (stores guarded)
    const float* arow = (const float*)Aptr + (size_t)ar * K + q * 8;
#pragma unroll
    for (int ks = 0; ks < KS; ++ks) {
      float4 v0 = *(const float4*)(arow + ks * 32);
      float4 v1 = *(const float4*)(arow + ks * 32 + 4);
      bf16x8 t;
      t[0] = (short)f2bf(v0.x); t[1] = (short)f2bf(v0.y);
      t[2] = (short)f2bf(v0.z); t[3] = (short)f2bf(v0.w);
      t[4] = (short)f2bf(v1.x); t[5] = (short)f2bf(v1.y);
      t[6] = (short)f2bf(v1.z); t[7] = (short)f2bf(v1.w);
      af[ks] = t;
    }
  } else {
    const u16* arow = (const u16*)Aptr + (size_t)(m0 + r) * K + q * 8;  // padded buffer
#pragma unroll
    for (int ks = 0; ks < KS; ++ks) af[ks] = *(const bf16x8*)(arow + ks * 32);
  }

  int node_base = m0 + q * 4;
#pragma unroll
  for (int h = 0; h < NH; ++h) {
    f32x4 acc[4];
#pragma unroll
    for (int c4 = 0; c4 < 4; ++c4) {
      acc[c4] = (f32x4){0.f, 0.f, 0.f, 0.f};
      const u16* bp = Bp + ((size_t)q * 256 + (h * 4 + c4) * 16 + r) * 8;
#pragma unroll
      for (int ks = 0; ks < KS; ++ks) {
        bf16x8 bf = *(const bf16x8*)(bp + (size_t)ks * 4 * 256 * 8);
        acc[c4] = __builtin_amdgcn_mfma_f32_16x16x32_bf16(af[ks], bf, acc[c4], 0, 0, 0);
      }
    }
    // epilogue for this head: alpha partials + packed bf16 stores
    float ps[4] = {0.f, 0.f, 0.f, 0.f}, pd[4] = {0.f, 0.f, 0.f, 0.f};
#pragma unroll
    for (int c4 = 0; c4 < 4; ++c4) {
      float sa = a_s[h * HID + c4 * 16 + r];
      float da = a_d[h * HID + c4 * 16 + r];
#pragma unroll
      for (int reg = 0; reg < 4; ++reg) {
        float v = acc[c4][reg];
        ps[reg] += v * sa;
        pd[reg] += v * da;
        int node = node_base + reg;
        if (node < M) hf16[(size_t)node * NC + (c4 * 16 + r) * NH + h] = f2bf(v);
      }
    }
#pragma unroll
    for (int reg = 0; reg < 4; ++reg) {
#pragma unroll
      for (int o = 1; o < 16; o <<= 1) {
        ps[reg] += __shfl_xor(ps[reg], o);
        pd[reg] += __shfl_xor(pd[reg], o);
      }
      int node = node_base + reg;
      if (r == 0 && node < M) {
        al_s[node * NH + h] = ps[reg];
        al_d[node * NH + h] = pd[reg];
      }
    }
  }
}

// ---------------- aggregation: one wave per destination node ----------------
// Mask-padded chunks of 8 (no tail path), depth-1 software pipeline on the
// gathers, denominator via shfl tree on the weight lanes. No max-shift:
// logits bounded ~|e|<20 => exp(e)/sum identical to reference's shifted softmax.
template <bool FINAL>
__global__ __launch_bounds__(256) void agg_kernel(const u16* __restrict__ hf16,
                                                  const float4* __restrict__ al_s4,
                                                  const float4* __restrict__ al_d4,
                                                  const int* __restrict__ offs, const int* __restrict__ csr_src,
                                                  const float* __restrict__ bias, void* __restrict__ out_v, int n) {
  int lane = threadIdx.x & 63;
  int node = blockIdx.x * 4 + (threadIdx.x >> 6);
  if (node >= n) return;
  float4 ad = al_d4[node];
  int lj = lane & 7;           // edge slot within chunk (weight lanes)
  int hsel = (lane >> 3) & 3;  // head handled by this lane in the weight phase
  float adv = hsel == 0 ? ad.x : (hsel == 1 ? ad.y : (hsel == 2 ? ad.z : ad.w));
  float c0 = 0.f, c1 = 0.f, c2 = 0.f, c3 = 0.f;
  float dacc = 0.f;            // per-head denom partial on lanes 0,8,16,24
  int s = offs[node], e = offs[node + 1];
  int nch = (e - s + 7) >> 3;
  int i = s;

  int vidx = 0;
  float4 as = make_float4(0.f, 0.f, 0.f, 0.f);
  ushort4 hv[8];
  if (nch > 0) {
    int idx = i + lj; if (idx >= e) idx = e - 1;   // clamp: masked by w=0 later
    vidx = csr_src[idx];
    as = al_s4[vidx];
#pragma unroll
    for (int j = 0; j < 8; ++j) {
      int sa = __builtin_amdgcn_readlane(vidx, j);
      hv[j] = ((const ushort4*)(hf16 + (size_t)sa * NC))[lane];
    }
  }

  for (int ch = 0; ch < nch; ++ch) {
    bool last = (ch + 1 == nch);
    // ---- weight phase (lanes 0..31 meaningful) ----
    float asv = hsel == 0 ? as.x : (hsel == 1 ? as.y : (hsel == 2 ? as.z : as.w));
    float ev = asv + adv;
    ev = ev >= 0.f ? ev : NEG * ev;
    float wv = __expf(ev);
    if (i + lj >= e) wv = 0.f;                     // mask padded slots
    float t = wv;
    t += __shfl_xor(t, 1); t += __shfl_xor(t, 2); t += __shfl_xor(t, 4);
    dacc += t;                                     // lanes 0,8,16,24 hold head sums
    // ---- prefetch next chunk ----
    int vidx_n = 0;
    float4 as_n = make_float4(0.f, 0.f, 0.f, 0.f);
    ushort4 hn[8];
    if (!last) {
      int idx = i + 8 + lj; if (idx >= e) idx = e - 1;
      vidx_n = csr_src[idx];
      as_n = al_s4[vidx_n];
#pragma unroll
      for (int j = 0; j < 8; ++j) {
        int sa = __builtin_amdgcn_readlane(vidx_n, j);
        hn[j] = ((const ushort4*)(hf16 + (size_t)sa * NC))[lane];
      }
    }
    // ---- accumulate current chunk ----
#pragma unroll
    for (int j = 0; j < 8; ++j) {
      float wx = readlane_f(wv, j);
      float wy = readlane_f(wv, 8 + j);
      float wz = readlane_f(wv, 16 + j);
      float ww = readlane_f(wv, 24 + j);
      c0 += wx * bf2f(hv[j].x);
      c1 += wy * bf2f(hv[j].y);
      c2 += wz * bf2f(hv[j].z);
      c3 += ww * bf2f(hv[j].w);
    }
    if (!last) {
      vidx = vidx_n; as = as_n;
#pragma unroll
      for (int j = 0; j < 8; ++j) hv[j] = hn[j];
    }
    i += 8;
  }
  float d0 = readlane_f(dacc, 0), d1 = readlane_f(dacc, 8);
  float d2 = readlane_f(dacc, 16), d3 = readlane_f(dacc, 24);
  float val = 0.25f * (c0 / (d0 + 1e-16f) + c1 / (d1 + 1e-16f) +
                       c2 / (d2 + 1e-16f) + c3 / (d3 + 1e-16f)) + bias[lane];
  if (!FINAL) {
    // layer-1 output: relu + bf16 (feeds layer-2 MFMA GEMM directly)
    ((u16*)out_v)[(size_t)node * HID + lane] = f2bf(fmaxf(val, 0.f));
  } else {
    float mx = val;
#pragma unroll
    for (int o = 32; o >= 1; o >>= 1) mx = fmaxf(mx, __shfl_xor(mx, o));
    float ex = __expf(val - mx);
    float sm = ex;
#pragma unroll
    for (int o = 32; o >= 1; o >>= 1) sm += __shfl_xor(sm, o);
    ((float*)out_v)[(size_t)node * HID + lane] = (val - mx) - logf(sm);
  }
}

// ---------------- launch ----------------
extern "C" void kernel_launch(void* const* d_in, const int* in_sizes, int n_in,
                              void* d_out, int out_size, void* d_ws, size_t ws_size,
                              hipStream_t stream) {
  const float* x   = (const float*)d_in[0];
  const int*   ei  = (const int*)d_in[1];   // int32 (JAX x64 disabled canonicalizes int64)
  const float* W1  = (const float*)d_in[2];
  const float* as1 = (const float*)d_in[3];
  const float* ad1 = (const float*)d_in[4];
  const float* b1  = (const float*)d_in[5];
  const float* W2  = (const float*)d_in[6];
  const float* as2 = (const float*)d_in[7];
  const float* ad2 = (const float*)d_in[8];
  const float* b2  = (const float*)d_in[9];
  float* out = (float*)d_out;

  const int N = NNODE;
  const int E = in_sizes[1] / 2;

  char* base = (char*)d_ws;
  size_t off = 0;
  auto alloc = [&](size_t bytes) -> void* {
    void* p = base + off;
    off += (bytes + 255) & ~(size_t)255;
    return p;
  };
  u16*    hf16   = (u16*)alloc((size_t)N * NC * 2);       // 25.6 MB packed [node][c][h]
  u16*    h1bf   = (u16*)alloc((size_t)MPAD * HID * 2);   // 6.4 MB bf16 layer-1 out (padded)
  u16*    Bp1    = (u16*)alloc((size_t)FIN * NC * 2);     // packed W1
  u16*    Bp2    = (u16*)alloc((size_t)HID * NC * 2);     // packed W2
  float*  al_s   = (float*)alloc((size_t)N * NH * 4);
  float*  al_d   = (float*)alloc((size_t)N * NH * 4);
  int*    deg    = (int*)alloc((size_t)N * 4);
  int*    offs   = (int*)alloc((size_t)(N + 1) * 4);
  int*    cursor = (int*)alloc((size_t)N * 4);
  int*    csr    = (int*)alloc((size_t)E * 4);
  int*    bsums  = (int*)alloc(256 * 4);
  int*    boffs  = (int*)alloc(256 * 4);

  const int nodeBlocks = (N + 3) / 4;           // 12500, wave per node
  const int edgeBlocks = (E + 255) / 256;       // 3125
  const int scanBlocks = (N + 255) / 256;       // 196
  const int gemmBlocks = MPAD / 64;             // 782

  // --- CSR build (shared by both layers) ---
  hipMemsetAsync(deg, 0, (size_t)N * 4, stream);
  count_deg<<<edgeBlocks, 256, 0, stream>>>(ei, deg, E);
  scan_phase1<<<scanBlocks, 256, 0, stream>>>(deg, bsums, N);
  scan_phase2<<<1, 256, 0, stream>>>(bsums, boffs, scanBlocks, offs + N);
  scan_phase3<<<scanBlocks, 256, 0, stream>>>(deg, boffs, offs, cursor, N);
  scatter_edges<<<edgeBlocks, 256, 0, stream>>>(ei, cursor, csr, E);

  // --- weight packing ---
  pack_W<<<(FIN * NC + 255) / 256, 256, 0, stream>>>(W1, Bp1, FIN * NC);
  pack_W<<<(HID * NC + 255) / 256, 256, 0, stream>>>(W2, Bp2, HID * NC);

  // --- layer 1 (A = x fp32, converted in-register) ---
  gemm_mfma<4, true><<<gemmBlocks, 256, 0, stream>>>(x, Bp1, as1, ad1, hf16, al_s, al_d, N);
  agg_kernel<false><<<nodeBlocks, 256, 0, stream>>>(hf16, (const float4*)al_s, (const float4*)al_d,
                                                    offs, csr, b1, h1bf, N);

  // --- layer 2 (A = h1bf bf16) ---
  gemm_mfma<2, false><<<gemmBlocks, 256, 0, stream>>>(h1bf, Bp2, as2, ad2, hf16, al_s, al_d, N);
  agg_kernel<true><<<nodeBlocks, 256, 0, stream>>>(hf16, (const float4*)al_s, (const float4*)al_d,
                                                   offs, csr, b2, out, N);
}